// Round 2
// baseline (7206.375 us; speedup 1.0000x reference)
//
#include <hip/hip_runtime.h>
#include <hip/hip_bf16.h>

typedef __hip_bfloat16 bf16;

#define BB 16
#define EE 2048
#define FF 8192
#define QQ 20
#define DD 256
#define WDIM 300
#define NWORD 50000
#define VERY_NEG_F (-1.0e11f)

static __device__ __forceinline__ float b2f(bf16 x){ return __bfloat162float(x); }
static __device__ __forceinline__ bf16 f2b(float x){ return __float2bfloat16(x); }
static __device__ __forceinline__ float sigm(float x){ return 1.f/(1.f+expf(-x)); }
// dtype-agnostic load of a raw float input: isf=1 -> fp32, isf=0 -> bf16
static __device__ __forceinline__ float ldf(const void* p, long i, int isf){
  return isf ? ((const float*)p)[i] : b2f(((const bf16*)p)[i]);
}

// ---------------- workspace offsets (bytes) ----------------
#define O_GX       0UL
#define O_QH       1310720UL
#define O_QNODE    1638400UL
#define O_RELLIN   1654784UL
#define O_WR       2270208UL
#define O_WMAX     2308672UL
#define O_WT       2308736UL
#define O_E2FS     2833024UL
#define O_PR       2964096UL
#define O_PRAGG    3095168UL
#define O_Q2EV     3226240UL
#define O_RELSELF  3242624UL
#define O_NORM     3858048UL
#define O_WNXT     4382336UL
#define O_PRSUM    4431488UL
#define O_F2EAGG   4431744UL
#define O_LEA      37986176UL
#define O_LEB      54763392UL
#define O_HEAD     71540608UL
#define O_ENTSELF  88317824UL
#define O_F2EEMB   105095040UL
#define O_FLAG     121872256UL   // int: 1 = inputs are fp32, 0 = bf16

// ---------------- dtype sniffer ----------------
// entity_emb ~ N(0,0.05). bf16 data: every ushort has exponent < 127.
// fp32 data: odd ushort = low mantissa bits -> exponent uniform -> ~25% >= 192.
__global__ __launch_bounds__(256) void k_sniff(const unsigned short* ee, int* flag){
  __shared__ int red[256];
  int c=0;
  for(int i=threadIdx.x;i<4096;i+=256){
    int ex=(ee[2*i]>>7)&0xFF;      // low half if fp32; first bf16 elem if bf16
    c += (ex>=192);
  }
  red[threadIdx.x]=c; __syncthreads();
  for(int o=128;o;o>>=1){ if(threadIdx.x<o) red[threadIdx.x]+=red[threadIdx.x+o]; __syncthreads(); }
  if(!threadIdx.x) flag[0] = (red[0]>64) ? 1 : 0;
}

// ---------------- LSTM precompute: gx = x @ w_ih^T + b_ih + b_hh ----------------
__global__ __launch_bounds__(256) void k_gx(const int* qtext, const void* wemb,
    const void* w_ih, const void* b_ih, const void* b_hh, float* gx, const int* dfl){
  const int isf=*dfl;
  int bt = blockIdx.x;
  __shared__ float xr[WDIM];
  int w = qtext[bt];
  for(int k=threadIdx.x;k<WDIM;k+=256) xr[k] = ldf(wemb,(long)w*WDIM+k,isf);
  __syncthreads();
  #pragma unroll
  for(int s=0;s<4;s++){
    int g = threadIdx.x + 256*s;
    float acc = ldf(b_ih,g,isf) + ldf(b_hh,g,isf);
    for(int k=0;k<WDIM;k++) acc += xr[k]*ldf(w_ih,(long)g*WDIM+k,isf);
    gx[bt*1024+g] = acc;
  }
}

// ---------------- LSTM: one block per batch ----------------
__global__ __launch_bounds__(1024) void k_lstm(const float* gx, const void* w_hh,
    float* qh, float* qnode, const int* dfl){
  const int isf=*dfl;
  int b = blockIdx.x;
  __shared__ float h[DD], c[DD], z[4*DD];
  int tid = threadIdx.x;
  if(tid<DD){ h[tid]=0.f; c[tid]=0.f; }
  __syncthreads();
  for(int t=0;t<QQ;t++){
    float acc = gx[(b*QQ+t)*1024 + tid];
    for(int j=0;j<DD;j++) acc += h[j]*ldf(w_hh,(long)tid*DD+j,isf);
    z[tid]=acc;
    __syncthreads();
    if(tid<DD){
      float zi=z[tid], zf=z[DD+tid], zg=z[2*DD+tid], zo=z[3*DD+tid];
      float ci = sigm(zf)*c[tid] + sigm(zi)*tanhf(zg);
      c[tid]=ci;
      float hh = sigm(zo)*tanhf(ci);
      h[tid]=hh;
      qh[(b*QQ+t)*DD+tid]=hh;
    }
    __syncthreads();
  }
  if(tid<DD) qnode[b*DD+tid]=h[tid];
}

// ---------------- rel_lin[r] = relation_emb[r] @ relation_lin_w^T + b ----------------
__global__ __launch_bounds__(256) void k_rel_lin(const void* remb, const void* rlw,
    const void* rlb, float* rel_lin, const int* dfl){
  const int isf=*dfl;
  int r = blockIdx.x;
  __shared__ float rr[2*WDIM];
  for(int k=threadIdx.x;k<2*WDIM;k+=256) rr[k]=ldf(remb,(long)r*2*WDIM+k,isf);
  __syncthreads();
  int d=threadIdx.x;
  float acc=ldf(rlb,d,isf);
  for(int k=0;k<2*WDIM;k++) acc += rr[k]*ldf(rlw,(long)d*2*WDIM+k,isf);
  rel_lin[r*DD+d]=acc;
}

// ---------------- sim(relation space) + masked softmax over q + Wr ----------------
__global__ __launch_bounds__(256) void k_simwr(const float* qh, const float* rel_lin,
    const int* qtext, float* Wr){
  int b = blockIdx.x, rc = blockIdx.y;
  __shared__ float qhb[QQ*DD];
  __shared__ float qm[QQ];
  for(int i=threadIdx.x;i<QQ*DD;i+=256) qhb[i]=qh[b*QQ*DD+i];
  if(threadIdx.x<QQ) qm[threadIdx.x] = (qtext[b*QQ+threadIdx.x]!=NWORD)?0.f:VERY_NEG_F;
  __syncthreads();
  int r = rc*256+threadIdx.x;
  if(r>=601) return;
  float s[QQ];
  #pragma unroll
  for(int q=0;q<QQ;q++) s[q]=0.f;
  for(int k=0;k<DD;k++){
    float rl = rel_lin[r*DD+k];
    #pragma unroll
    for(int q=0;q<QQ;q++) s[q] += qhb[q*DD+k]*rl;
  }
  float m=-1e30f;
  #pragma unroll
  for(int q=0;q<QQ;q++){ s[q]*=0.0625f; m=fmaxf(m, s[q]+qm[q]); }
  float sum=0.f, w=0.f;
  #pragma unroll
  for(int q=0;q<QQ;q++){ float p=expf(s[q]+qm[q]-m); sum+=p; w+=p*s[q]; }
  Wr[b*601+r] = w/sum;
}

// ---------------- Wmax[b] = max_f Wr[b, rel[b,f]] ----------------
__global__ __launch_bounds__(256) void k_wmax(const float* Wr, const int* rel, float* wmax){
  int b=blockIdx.x; __shared__ float red[256];
  float m=-1e30f;
  for(int f=threadIdx.x;f<FF;f+=256) m=fmaxf(m, Wr[b*601+rel[b*FF+f]]);
  red[threadIdx.x]=m; __syncthreads();
  for(int o=128;o;o>>=1){ if(threadIdx.x<o) red[threadIdx.x]=fmaxf(red[threadIdx.x],red[threadIdx.x+o]); __syncthreads(); }
  if(!threadIdx.x) wmax[b]=red[0];
}

// ---------------- W_tilde + scatter e2f_softmax ----------------
__global__ __launch_bounds__(256) void k_wt(const float* Wr, const int* rel,
    const float* wmax, const int* e2f, float* wt, float* e2fs){
  int i = blockIdx.x*256+threadIdx.x;
  int b = i>>13;
  float v = expf(Wr[b*601+rel[i]] - wmax[b]);
  wt[i]=v;
  atomicAdd(e2fs + (b<<11) + e2f[i], v);
}

__global__ __launch_bounds__(256) void k_prinit(const void* adj, float* pr, const int* dfl){
  const int isf=*dfl;
  int i=blockIdx.x*256+threadIdx.x;
  pr[i]=ldf(adj,i,isf);
}

// ---------------- generic tiled fp32 GEMM: C[M,256] = A[M,K] @ W[256,K]^T (+bias) ----------------
struct GemmP {
  int M, K, relu;
  const void* W; long Woff; const void* bias; long bOff;
  const bf16* Abf;
  const int* idx; const void* emb;                       // mode 0
  const float* relself; const int* rel; const int* e2f;  // mode 2
  const float* normv; const bf16* headb;
  const float* q2ev; const bf16* f2eb;                   // mode 3
  bf16* outb; float* outat; const int* f2e;
  const int* dfl;
};

template<int MODE>
__global__ __launch_bounds__(256) void k_gemm(GemmP p){
  const int isf=*p.dfl;
  const int m0 = blockIdx.x*64, n0 = blockIdx.y*64;
  __shared__ float As[16][68], Bs[16][68];
  float acc[4][4]={};
  const int tid=threadIdx.x, tm=tid&15, tn=tid>>4;
  for(int k0=0;k0<p.K;k0+=16){
    #pragma unroll
    for(int s=0;s<4;s++){
      int e=tid+256*s; int kk=e&15, nn=e>>4; int kg=k0+kk;
      Bs[kk][nn] = (kg<p.K)? ldf(p.W, p.Woff+(long)(n0+nn)*p.K+kg, isf) : 0.f;
    }
    #pragma unroll
    for(int s=0;s<4;s++){
      int e=tid+256*s; int kk=e&15, mm=e>>4; int kg=k0+kk; int row=m0+mm;
      float v=0.f;
      if(kg<p.K){
        if(MODE==0){ int ent=p.idx[row]; v=ldf(p.emb,(long)ent*WDIM+kg,isf); }
        else if(MODE==1){ v=b2f(p.Abf[row*DD+kg]); }
        else if(MODE==2){
          int b=row>>13; int rr=p.rel[row]; int ee=p.e2f[row];
          v=fmaxf(p.relself[rr*DD+kg] + b2f(p.headb[((b<<11)+ee)*DD+kg]),0.f)*p.normv[row];
        } else {
          int b=row>>11;
          if(kg<DD) v=b2f(p.Abf[row*DD+kg]);
          else if(kg<2*DD) v=p.q2ev[(b<<8)+(kg-DD)];
          else v=3.f*b2f(p.f2eb[row*DD+(kg-2*DD)]);
        }
      }
      As[kk][mm]=v;
    }
    __syncthreads();
    #pragma unroll
    for(int kk=0;kk<16;kk++){
      float a[4],bv[4];
      #pragma unroll
      for(int i=0;i<4;i++){ a[i]=As[kk][tm*4+i]; bv[i]=Bs[kk][tn*4+i]; }
      #pragma unroll
      for(int i=0;i<4;i++)
        #pragma unroll
        for(int j=0;j<4;j++) acc[i][j]+=a[i]*bv[j];
    }
    __syncthreads();
  }
  #pragma unroll
  for(int i=0;i<4;i++){
    int row=m0+tm*4+i;
    #pragma unroll
    for(int j=0;j<4;j++){
      int n=n0+tn*4+j;
      float cval=acc[i][j]+ldf(p.bias,p.bOff+n,isf);
      if(MODE==2){
        int b=row>>13;
        atomicAdd(p.outat + ((b<<11)+p.f2e[row])*DD + n, cval);
      } else {
        if(p.relu) cval=fmaxf(cval,0.f);
        p.outb[row*DD+n]=f2b(cval);
      }
    }
  }
}

// ---------------- per-layer small mats: relself (601 rows) + q2e_vec (16 rows) ----------------
__global__ __launch_bounds__(256) void k_small(const float* rel_lin,
    const void* selfw, long swOff, const void* selfb, long sbOff,
    const float* qnode, const void* q2ew, long qwOff, const void* q2eb, long qbOff,
    float* relself, float* q2ev, const int* dfl){
  const int isf=*dfl;
  __shared__ float xr[DD];
  int d=threadIdx.x;
  if(blockIdx.x<601){
    int r=blockIdx.x;
    xr[d]=rel_lin[r*DD+d]; __syncthreads();
    float acc=ldf(selfb,sbOff+d,isf);
    for(int k=0;k<DD;k++) acc+=xr[k]*ldf(selfw,swOff+(long)d*DD+k,isf);
    relself[r*DD+d]=acc;
  } else {
    int b=blockIdx.x-601;
    xr[d]=qnode[(b<<8)+d]; __syncthreads();
    float acc=ldf(q2eb,qbOff+d,isf);
    for(int k=0;k<DD;k++) acc+=xr[k]*ldf(q2ew,qwOff+(long)d*DD+k,isf);
    q2ev[(b<<8)+d]=acc;
  }
}

// ---------------- norm + scatter pagerank numerator ----------------
__global__ __launch_bounds__(256) void k_norm(const float* wt, const float* pr,
    const float* e2fs, const int* e2f, const int* f2e, float* normv, float* pragg){
  int i=blockIdx.x*256+threadIdx.x;
  int b=i>>13;
  int e=e2f[i];
  float v=wt[i]*pr[(b<<11)+e]/fmaxf(e2fs[(b<<11)+e],1e-10f);
  normv[i]=v;
  atomicAdd(pragg+(b<<11)+f2e[i], v);
}

__global__ __launch_bounds__(256) void k_f2e(const bf16* entself, const float* agg, bf16* f2eemb){
  int i=blockIdx.x*256+threadIdx.x;
  f2eemb[i]=f2b(fmaxf(b2f(entself[i])+agg[i],0.f));
}

__global__ __launch_bounds__(256) void k_prupd(const float* pragg, float* pr){
  int i=blockIdx.x*256+threadIdx.x;
  pr[i]=0.8f*pragg[i]+0.2f*pr[i];
}

// ---------------- wnxt[b,:] = sum_e pr*nxt; prsum[b] = sum_e pr ----------------
__global__ __launch_bounds__(256) void k_wnxt(const float* pr, const bf16* le,
    const bf16* f2e, const float* q2ev, float* wnxt, float* prsum){
  int b=blockIdx.x, d=threadIdx.x;
  float a1=0.f, a3=0.f, ap=0.f;
  for(int e=0;e<EE;e++){
    float p=pr[(b<<11)+e];
    int base=((b<<11)+e)<<8;
    a1+=p*b2f(le[base+d]);
    a3+=p*b2f(f2e[base+d]);
    ap+=p;
  }
  wnxt[b*768+d]=a1;
  wnxt[b*768+DD+d]=ap*q2ev[(b<<8)+d];
  wnxt[b*768+2*DD+d]=3.f*a3;
  if(d==0) prsum[b]=ap;
}

__global__ __launch_bounds__(256) void k_qnode(const float* wnxt, const float* prsum,
    const void* w, long wOff, const void* bias, long bOff, float* qnode, const int* dfl){
  const int isf=*dfl;
  int b=blockIdx.x, d=threadIdx.x;
  __shared__ float xr[768];
  for(int k=threadIdx.x;k<768;k+=256) xr[k]=wnxt[b*768+k];
  __syncthreads();
  float acc=0.f;
  for(int k=0;k<768;k++) acc+=xr[k]*ldf(w,wOff+(long)d*768+k,isf);
  qnode[(b<<8)+d]=acc+prsum[b]*ldf(bias,bOff+d,isf);
}

// ---------------- score: one wave per output; dual-dtype store ----------------
__global__ __launch_bounds__(256) void k_score(const bf16* le, const void* sw,
    const void* sb, void* out, const int* dfl){
  const int isf=*dfl;
  int o=blockIdx.x*4 + (threadIdx.x>>6);
  int lane=threadIdx.x&63;
  float acc=0.f;
  int base=o*DD+lane*4;
  #pragma unroll
  for(int i=0;i<4;i++) acc+=b2f(le[base+i])*ldf(sw,lane*4+i,isf);
  for(int off=32;off;off>>=1) acc+=__shfl_down(acc,off,64);
  if(!lane){
    float v=acc+ldf(sb,0,isf);
    if(isf) ((float*)out)[o]=v; else ((bf16*)out)[o]=f2b(v);
  }
}

// ---------------- host ----------------
extern "C" void kernel_launch(void* const* d_in, const int* in_sizes, int n_in,
                              void* d_out, int out_size, void* d_ws, size_t ws_size,
                              hipStream_t stream){
  const int*  local_entity=(const int*)d_in[0];
  const void* q2e_adj     =d_in[1];
  const int*  kb_fact_rel =(const int*)d_in[2];
  const int*  query_text  =(const int*)d_in[3];
  const int*  e2f_ent     =(const int*)d_in[5];
  const int*  f2e_ent     =(const int*)d_in[6];
  const void* word_emb    =d_in[7];
  const void* entity_emb  =d_in[8];
  const void* relation_emb=d_in[9];
  const void* entity_lin_w=d_in[10];
  const void* entity_lin_b=d_in[11];
  const void* relation_lin_w=d_in[12];
  const void* relation_lin_b=d_in[13];
  const void* lstm_w_ih   =d_in[14];
  const void* lstm_w_hh   =d_in[15];
  const void* lstm_b_ih   =d_in[16];
  const void* lstm_b_hh   =d_in[17];
  const void* q2e_w       =d_in[18];
  const void* q2e_b       =d_in[19];
  const void* e2q_w       =d_in[20];
  const void* e2q_b       =d_in[21];
  const void* e2e_w       =d_in[22];
  const void* e2e_b       =d_in[23];
  const void* kb_head_w   =d_in[24];
  const void* kb_head_b   =d_in[25];
  const void* kb_tail_w   =d_in[26];
  const void* kb_tail_b   =d_in[27];
  const void* kb_self_w   =d_in[28];
  const void* kb_self_b   =d_in[29];
  const void* score_w     =d_in[30];
  const void* score_b     =d_in[31];

  char* ws=(char*)d_ws;
  float* gx      =(float*)(ws+O_GX);
  float* qh      =(float*)(ws+O_QH);
  float* qnode   =(float*)(ws+O_QNODE);
  float* rel_lin =(float*)(ws+O_RELLIN);
  float* Wr      =(float*)(ws+O_WR);
  float* wmax    =(float*)(ws+O_WMAX);
  float* wt      =(float*)(ws+O_WT);
  float* e2fs    =(float*)(ws+O_E2FS);
  float* pr      =(float*)(ws+O_PR);
  float* pragg   =(float*)(ws+O_PRAGG);
  float* q2ev    =(float*)(ws+O_Q2EV);
  float* relself =(float*)(ws+O_RELSELF);
  float* normv   =(float*)(ws+O_NORM);
  float* wnxt    =(float*)(ws+O_WNXT);
  float* prsum   =(float*)(ws+O_PRSUM);
  float* f2eagg  =(float*)(ws+O_F2EAGG);
  bf16*  leA     =(bf16*)(ws+O_LEA);
  bf16*  leB     =(bf16*)(ws+O_LEB);
  bf16*  headb   =(bf16*)(ws+O_HEAD);
  bf16*  entself =(bf16*)(ws+O_ENTSELF);
  bf16*  f2eemb  =(bf16*)(ws+O_F2EEMB);
  int*   dflag   =(int*)(ws+O_FLAG);

  k_sniff<<<1,256,0,stream>>>((const unsigned short*)entity_emb, dflag);

  k_gx   <<<BB*QQ,256,0,stream>>>(query_text, word_emb, lstm_w_ih, lstm_b_ih, lstm_b_hh, gx, dflag);
  k_lstm <<<BB,1024,0,stream>>>(gx, lstm_w_hh, qh, qnode, dflag);
  k_rel_lin<<<601,256,0,stream>>>(relation_emb, relation_lin_w, relation_lin_b, rel_lin, dflag);
  k_simwr<<<dim3(BB,3),256,0,stream>>>(qh, rel_lin, query_text, Wr);
  k_wmax <<<BB,256,0,stream>>>(Wr, kb_fact_rel, wmax);
  hipMemsetAsync(e2fs, 0, (size_t)BB*EE*4, stream);
  k_wt   <<<BB*FF/256,256,0,stream>>>(Wr, kb_fact_rel, wmax, e2f_ent, wt, e2fs);
  k_prinit<<<BB*EE/256,256,0,stream>>>(q2e_adj, pr, dflag);

  {
    GemmP p{}; p.M=BB*EE; p.K=WDIM; p.W=entity_lin_w; p.Woff=0; p.bias=entity_lin_b; p.bOff=0;
    p.idx=local_entity; p.emb=entity_emb; p.outb=leA; p.relu=0; p.dfl=dflag;
    k_gemm<0><<<dim3(BB*EE/64,4),256,0,stream>>>(p);
  }

  bf16* le_cur=leA; bf16* le_nxt=leB;
  for(int i=0;i<3;i++){
    k_small<<<617,256,0,stream>>>(rel_lin, kb_self_w,(long)i*DD*DD, kb_self_b,(long)i*DD,
        qnode, q2e_w,(long)i*DD*DD, q2e_b,(long)i*DD, relself, q2ev, dflag);
    {
      GemmP p{}; p.M=BB*EE; p.K=DD; p.W=kb_head_w; p.Woff=(long)i*DD*DD; p.bias=kb_head_b; p.bOff=(long)i*DD;
      p.Abf=le_cur; p.outb=headb; p.relu=0; p.dfl=dflag;
      k_gemm<1><<<dim3(BB*EE/64,4),256,0,stream>>>(p);
    }
    {
      GemmP p{}; p.M=BB*EE; p.K=DD; p.W=kb_self_w; p.Woff=(long)i*DD*DD; p.bias=kb_self_b; p.bOff=(long)i*DD;
      p.Abf=le_cur; p.outb=entself; p.relu=0; p.dfl=dflag;
      k_gemm<1><<<dim3(BB*EE/64,4),256,0,stream>>>(p);
    }
    hipMemsetAsync(f2eagg, 0, (size_t)BB*EE*DD*4, stream);
    hipMemsetAsync(pragg, 0, (size_t)BB*EE*4, stream);
    k_norm<<<BB*FF/256,256,0,stream>>>(wt, pr, e2fs, e2f_ent, f2e_ent, normv, pragg);
    {
      GemmP p{}; p.M=BB*FF; p.K=DD; p.W=kb_tail_w; p.Woff=(long)i*DD*DD; p.bias=kb_tail_b; p.bOff=(long)i*DD;
      p.relself=relself; p.rel=kb_fact_rel; p.e2f=e2f_ent; p.normv=normv; p.headb=headb;
      p.outat=f2eagg; p.f2e=f2e_ent; p.dfl=dflag;
      k_gemm<2><<<dim3(BB*FF/64,4),256,0,stream>>>(p);
    }
    k_f2e  <<<BB*EE*DD/256,256,0,stream>>>(entself, f2eagg, f2eemb);
    k_prupd<<<BB*EE/256,256,0,stream>>>(pragg, pr);
    k_wnxt <<<BB,256,0,stream>>>(pr, le_cur, f2eemb, q2ev, wnxt, prsum);
    k_qnode<<<BB,256,0,stream>>>(wnxt, prsum, e2q_w,(long)i*DD*768, e2q_b,(long)i*DD, qnode, dflag);
    {
      GemmP p{}; p.M=BB*EE; p.K=768; p.W=e2e_w; p.Woff=(long)i*DD*768; p.bias=e2e_b; p.bOff=(long)i*DD;
      p.Abf=le_cur; p.q2ev=q2ev; p.f2eb=f2eemb; p.outb=le_nxt; p.relu=1; p.dfl=dflag;
      k_gemm<3><<<dim3(BB*EE/64,4),256,0,stream>>>(p);
    }
    bf16* t=le_cur; le_cur=le_nxt; le_nxt=t;
  }

  k_score<<<BB*EE/4,256,0,stream>>>(le_cur, score_w, score_b, d_out, dflag);
}

// Round 3
// 4623.600 us; speedup vs baseline: 1.5586x; 1.5586x over previous
//
#include <hip/hip_runtime.h>
#include <hip/hip_bf16.h>

typedef __hip_bfloat16 bf16;

#define BB 16
#define EE 2048
#define FF 8192
#define QQ 20
#define DD 256
#define WDIM 300
#define NWORD 50000
#define VERY_NEG_F (-1.0e11f)

static __device__ __forceinline__ float b2f(bf16 x){ return __bfloat162float(x); }
static __device__ __forceinline__ bf16 f2b(float x){ return __float2bfloat16(x); }
static __device__ __forceinline__ float sigm(float x){ return 1.f/(1.f+expf(-x)); }
// 4 consecutive bf16 -> 4 floats, one 8B load
static __device__ __forceinline__ void ld4bf(const bf16* p, float v[4]){
  short4 s = *(const short4*)p;
  v[0]=b2f(*(const bf16*)&s.x); v[1]=b2f(*(const bf16*)&s.y);
  v[2]=b2f(*(const bf16*)&s.z); v[3]=b2f(*(const bf16*)&s.w);
}

// ---------------- workspace offsets (bytes, all 16B-aligned) ----------------
#define O_GX       0UL
#define O_QH       1310720UL
#define O_QNODE    1638400UL
#define O_RELLIN   1654784UL
#define O_WR       2270208UL
#define O_WMAX     2308672UL
#define O_WT       2308736UL
#define O_E2FS     2833024UL
#define O_PR       2964096UL
#define O_PRAGG    3095168UL
#define O_Q2EV     3226240UL
#define O_RELSELF  3242624UL
#define O_NORM     3858048UL
#define O_WNXT     4382336UL   // 16*768*4 = 49152
#define O_PRSUM    4431488UL   // 64
#define O_F2EAGG   4431744UL   // 33554432
#define O_LEA      37986176UL
#define O_LEB      54763392UL
#define O_HEAD     71540608UL
#define O_ENTSELF  88317824UL
#define O_F2EEMB   105095040UL
#define O_FLAG     121872256UL
#define O_CVT      121872384UL // bf16 canonical weights, 2773252 elems -> end ~127.4MB

// canonical element offsets within O_CVT
#define C_ELW   0
#define C_ELB   76800
#define C_RLW   77056
#define C_RLB   230656
#define C_WIH   230912
#define C_WHH   538112
#define C_BIH   800256
#define C_BHH   801280
#define C_Q2EW  802304
#define C_Q2EB  998912
#define C_E2QW  999680
#define C_E2QB  1589504
#define C_E2EW  1590272
#define C_E2EB  2180096
#define C_KHW   2180864
#define C_KHB   2377472
#define C_KTW   2378240
#define C_KTB   2574848
#define C_KSW   2575616
#define C_KSB   2772224
#define C_SCW   2772992
#define C_SCB   2773248

// ---------------- dtype sniffer (unchanged — verified r2) ----------------
__global__ __launch_bounds__(256) void k_sniff(const unsigned short* ee, int* flag){
  __shared__ int red[256];
  int c=0;
  for(int i=threadIdx.x;i<4096;i+=256){
    int ex=(ee[2*i]>>7)&0xFF;
    c += (ex>=192);
  }
  red[threadIdx.x]=c; __syncthreads();
  for(int o=128;o;o>>=1){ if(threadIdx.x<o) red[threadIdx.x]+=red[threadIdx.x+o]; __syncthreads(); }
  if(!threadIdx.x) flag[0] = (red[0]>64) ? 1 : 0;
}

// ---------------- batched weight canonicalization -> bf16 ----------------
struct CvtJobs{ const void* src[22]; bf16* dst[22]; int n[22]; };
__global__ __launch_bounds__(256) void k_cvt(CvtJobs J, const int* dfl){
  const int isf=*dfl;
  int j=blockIdx.y;
  int n=J.n[j];
  int i4=(blockIdx.x*256+threadIdx.x)*4;
  if(i4>=n) return;
  bf16* d=J.dst[j]+i4;
  if(isf){
    const float* s=(const float*)J.src[j]+i4;
    if(i4+4<=n){
      float4 t=*(const float4*)s;
      bf16 b0=f2b(t.x),b1=f2b(t.y),b2=f2b(t.z),b3=f2b(t.w);
      unsigned short u[4];
      u[0]=*(unsigned short*)&b0; u[1]=*(unsigned short*)&b1;
      u[2]=*(unsigned short*)&b2; u[3]=*(unsigned short*)&b3;
      *(short4*)d=*(short4*)u;
    } else for(int r=0;i4+r<n;r++) d[r]=f2b(s[r]);
  } else {
    const bf16* s=(const bf16*)J.src[j]+i4;
    if(i4+4<=n) *(short4*)d=*(const short4*)s;
    else for(int r=0;i4+r<n;r++) d[r]=s[r];
  }
}

// ---------------- gx = wemb[qtext] @ w_ih^T + b_ih + b_hh ----------------
__global__ __launch_bounds__(256) void k_gx(const int* qtext, const void* wemb,
    const bf16* wih, const bf16* bih, const bf16* bhh, float* gx, const int* dfl){
  const int isf=*dfl;
  int bt=blockIdx.x;
  __shared__ float xr[WDIM];
  int w=qtext[bt];
  for(int k4=threadIdx.x*4;k4<WDIM;k4+=1024){
    if(isf){ float4 t=*(const float4*)((const float*)wemb+(long)w*WDIM+k4);
             xr[k4]=t.x;xr[k4+1]=t.y;xr[k4+2]=t.z;xr[k4+3]=t.w; }
    else   { float v[4]; ld4bf((const bf16*)wemb+(long)w*WDIM+k4,v);
             xr[k4]=v[0];xr[k4+1]=v[1];xr[k4+2]=v[2];xr[k4+3]=v[3]; }
  }
  __syncthreads();
  #pragma unroll
  for(int s=0;s<4;s++){
    int g=threadIdx.x+256*s;
    float acc=b2f(bih[g])+b2f(bhh[g]);
    const bf16* wr=wih+(long)g*WDIM;
    for(int k4=0;k4<WDIM;k4+=4){
      float v[4]; ld4bf(wr+k4,v);
      acc+=v[0]*xr[k4]+v[1]*xr[k4+1]+v[2]*xr[k4+2]+v[3]*xr[k4+3];
    }
    gx[bt*1024+g]=acc;
  }
}

// ---------------- LSTM recurrence: vectorized w_hh ----------------
__global__ __launch_bounds__(1024) void k_lstm(const float* gx, const bf16* whh,
    float* qh, float* qnode){
  int b = blockIdx.x;
  __shared__ float h[DD], c[DD], z[4*DD];
  int tid = threadIdx.x;
  if(tid<DD){ h[tid]=0.f; c[tid]=0.f; }
  __syncthreads();
  const bf16* wr = whh + (long)tid*DD;
  for(int t=0;t<QQ;t++){
    float acc = gx[(b*QQ+t)*1024 + tid];
    #pragma unroll 8
    for(int j=0;j<64;j++){
      float w[4]; ld4bf(wr+j*4,w);
      float4 hv=*(const float4*)&h[j*4];
      acc += w[0]*hv.x+w[1]*hv.y+w[2]*hv.z+w[3]*hv.w;
    }
    z[tid]=acc;
    __syncthreads();
    if(tid<DD){
      float zi=z[tid], zf=z[DD+tid], zg=z[2*DD+tid], zo=z[3*DD+tid];
      float ci = sigm(zf)*c[tid] + sigm(zi)*tanhf(zg);
      c[tid]=ci;
      float hh = sigm(zo)*tanhf(ci);
      h[tid]=hh;
      qh[(b*QQ+t)*DD+tid]=hh;
    }
    __syncthreads();
  }
  if(tid<DD) qnode[b*DD+tid]=h[tid];
}

// ---------------- rel_lin[r] = relation_emb[r] @ relation_lin_w^T + b ----------------
__global__ __launch_bounds__(256) void k_rel_lin(const void* remb, const bf16* rlw,
    const bf16* rlb, float* rel_lin, const int* dfl){
  const int isf=*dfl;
  int r=blockIdx.x;
  __shared__ float rr[2*WDIM];
  for(int k4=threadIdx.x*4;k4<2*WDIM;k4+=1024){
    if(isf){ float4 t=*(const float4*)((const float*)remb+(long)r*2*WDIM+k4);
             rr[k4]=t.x;rr[k4+1]=t.y;rr[k4+2]=t.z;rr[k4+3]=t.w; }
    else   { float v[4]; ld4bf((const bf16*)remb+(long)r*2*WDIM+k4,v);
             rr[k4]=v[0];rr[k4+1]=v[1];rr[k4+2]=v[2];rr[k4+3]=v[3]; }
  }
  __syncthreads();
  int d=threadIdx.x;
  float acc=b2f(rlb[d]);
  const bf16* wr=rlw+(long)d*2*WDIM;
  for(int k4=0;k4<2*WDIM;k4+=4){
    float v[4]; ld4bf(wr+k4,v);
    acc+=v[0]*rr[k4]+v[1]*rr[k4+1]+v[2]*rr[k4+2]+v[3]*rr[k4+3];
  }
  rel_lin[r*DD+d]=acc;
}

// ---------------- sim + masked softmax over q + Wr (relation space) ----------------
__global__ __launch_bounds__(256) void k_simwr(const float* qh, const float* rel_lin,
    const int* qtext, float* Wr){
  int b = blockIdx.x, rc = blockIdx.y;
  __shared__ float qhb[QQ*DD];
  __shared__ float qm[QQ];
  for(int i=threadIdx.x;i<QQ*DD;i+=256) qhb[i]=qh[b*QQ*DD+i];
  if(threadIdx.x<QQ) qm[threadIdx.x] = (qtext[b*QQ+threadIdx.x]!=NWORD)?0.f:VERY_NEG_F;
  __syncthreads();
  int r = rc*256+threadIdx.x;
  if(r>=601) return;
  float s[QQ];
  #pragma unroll
  for(int q=0;q<QQ;q++) s[q]=0.f;
  for(int k=0;k<DD;k++){
    float rl = rel_lin[r*DD+k];
    #pragma unroll
    for(int q=0;q<QQ;q++) s[q] += qhb[q*DD+k]*rl;
  }
  float m=-1e30f;
  #pragma unroll
  for(int q=0;q<QQ;q++){ s[q]*=0.0625f; m=fmaxf(m, s[q]+qm[q]); }
  float sum=0.f, w=0.f;
  #pragma unroll
  for(int q=0;q<QQ;q++){ float p=expf(s[q]+qm[q]-m); sum+=p; w+=p*s[q]; }
  Wr[b*601+r] = w/sum;
}

// ---------------- Wmax / W_tilde / e2f_softmax ----------------
__global__ __launch_bounds__(256) void k_wmax(const float* Wr, const int* rel, float* wmax){
  int b=blockIdx.x; __shared__ float red[256];
  float m=-1e30f;
  for(int f=threadIdx.x;f<FF;f+=256) m=fmaxf(m, Wr[b*601+rel[b*FF+f]]);
  red[threadIdx.x]=m; __syncthreads();
  for(int o=128;o;o>>=1){ if(threadIdx.x<o) red[threadIdx.x]=fmaxf(red[threadIdx.x],red[threadIdx.x+o]); __syncthreads(); }
  if(!threadIdx.x) wmax[b]=red[0];
}

__global__ __launch_bounds__(256) void k_wt(const float* Wr, const int* rel,
    const float* wmax, const int* e2f, float* wt, float* e2fs){
  int i = blockIdx.x*256+threadIdx.x;
  int b = i>>13;
  float v = expf(Wr[b*601+rel[i]] - wmax[b]);
  wt[i]=v;
  atomicAdd(e2fs + (b<<11) + e2f[i], v);
}

__global__ __launch_bounds__(256) void k_prinit(const void* adj, float* pr, const int* dfl){
  const int isf=*dfl;
  int i4=(blockIdx.x*256+threadIdx.x)*4;
  if(isf){ *(float4*)(pr+i4)=*(const float4*)((const float*)adj+i4); }
  else { float v[4]; ld4bf((const bf16*)adj+i4,v);
         float4 t; t.x=v[0];t.y=v[1];t.z=v[2];t.w=v[3]; *(float4*)(pr+i4)=t; }
}

// ---------------- tiled GEMM: C[M,256] = A[M,K] @ W[256,K]^T + bias ----------------
// 128x128 tile, 8x8 micro-tile. MODE 0: A=entity_emb gather; 1: A=bf16 buf;
// 2: A=relu(relself[rel]+head[e2f])*norm -> atomic scatter by f2e; 3: A=concat (K=768) -> relu
struct GemmP {
  int M, K, relu;
  const bf16* W; const bf16* bias;
  const bf16* Abf;
  const int* idx; const void* emb;
  const float* relself; const int* rel; const int* e2f;
  const float* normv; const bf16* headb;
  const float* q2ev; const bf16* f2eb;
  bf16* outb; float* outat; const int* f2e;
  const int* dfl;
};

template<int MODE>
__global__ __launch_bounds__(256) void k_gemm(GemmP p){
  const int m0 = blockIdx.x*128, n0 = blockIdx.y*128;
  __shared__ float As[16][132], Bs[16][132];
  float acc[8][8]={};
  const int tid=threadIdx.x, tm=tid&15, tn=tid>>4;
  const int isf = (MODE==0)? *p.dfl : 0;
  for(int k0=0;k0<p.K;k0+=16){
    #pragma unroll
    for(int s=0;s<2;s++){
      int e=tid+256*s; int nn=e>>2, q=e&3; int kg=k0+q*4;
      float v[4]={0.f,0.f,0.f,0.f};
      if(kg+4<=p.K) ld4bf(p.W+(long)(n0+nn)*p.K+kg, v);
      Bs[q*4+0][nn]=v[0]; Bs[q*4+1][nn]=v[1]; Bs[q*4+2][nn]=v[2]; Bs[q*4+3][nn]=v[3];
    }
    #pragma unroll
    for(int s=0;s<2;s++){
      int e=tid+256*s; int mm=e>>2, q=e&3; int kg=k0+q*4; int row=m0+mm;
      float v[4]={0.f,0.f,0.f,0.f};
      if(MODE==0){
        if(kg+4<=p.K){
          int ent=p.idx[row];
          if(isf){ float4 t=*(const float4*)((const float*)p.emb+(long)ent*WDIM+kg);
                   v[0]=t.x;v[1]=t.y;v[2]=t.z;v[3]=t.w; }
          else ld4bf((const bf16*)p.emb+(long)ent*WDIM+kg, v);
        }
      } else if(MODE==1){
        ld4bf(p.Abf+(long)row*DD+kg, v);
      } else if(MODE==2){
        int b=row>>13; int rr=p.rel[row]; int ee=p.e2f[row]; float nv=p.normv[row];
        float4 rs=*(const float4*)&p.relself[rr*DD+kg];
        float hb[4]; ld4bf(p.headb+(long)(((b<<11)+ee)*DD+kg), hb);
        v[0]=fmaxf(rs.x+hb[0],0.f)*nv; v[1]=fmaxf(rs.y+hb[1],0.f)*nv;
        v[2]=fmaxf(rs.z+hb[2],0.f)*nv; v[3]=fmaxf(rs.w+hb[3],0.f)*nv;
      } else {
        int b=row>>11;
        if(kg<DD) ld4bf(p.Abf+(long)row*DD+kg, v);
        else if(kg<2*DD){ float4 t=*(const float4*)&p.q2ev[(b<<8)+kg-DD];
                          v[0]=t.x;v[1]=t.y;v[2]=t.z;v[3]=t.w; }
        else { ld4bf(p.f2eb+(long)row*DD+(kg-2*DD), v);
               v[0]*=3.f;v[1]*=3.f;v[2]*=3.f;v[3]*=3.f; }
      }
      As[q*4+0][mm]=v[0]; As[q*4+1][mm]=v[1]; As[q*4+2][mm]=v[2]; As[q*4+3][mm]=v[3];
    }
    __syncthreads();
    #pragma unroll
    for(int kk=0;kk<16;kk++){
      float a[8],bv[8];
      *(float4*)(a)   = *(const float4*)&As[kk][tm*8];
      *(float4*)(a+4) = *(const float4*)&As[kk][tm*8+4];
      *(float4*)(bv)  = *(const float4*)&Bs[kk][tn*8];
      *(float4*)(bv+4)= *(const float4*)&Bs[kk][tn*8+4];
      #pragma unroll
      for(int i=0;i<8;i++)
        #pragma unroll
        for(int j=0;j<8;j++) acc[i][j]+=a[i]*bv[j];
    }
    __syncthreads();
  }
  float bb[8];
  #pragma unroll
  for(int j=0;j<8;j++) bb[j]=b2f(p.bias[n0+tn*8+j]);
  #pragma unroll
  for(int i=0;i<8;i++){
    int row=m0+tm*8+i;
    if(MODE==2){
      int b=row>>13;
      float* dst=p.outat + (long)(((b<<11)+p.f2e[row])*DD + n0+tn*8);
      #pragma unroll
      for(int j=0;j<8;j++) atomicAdd(dst+j, acc[i][j]+bb[j]);
    } else {
      unsigned short u[8];
      #pragma unroll
      for(int j=0;j<8;j++){
        float cv=acc[i][j]+bb[j];
        if(p.relu) cv=fmaxf(cv,0.f);
        bf16 t=f2b(cv); u[j]=*(unsigned short*)&t;
      }
      *(short4*)(p.outb+(long)row*DD+n0+tn*8)   = *(short4*)u;
      *(short4*)(p.outb+(long)row*DD+n0+tn*8+4) = *(short4*)(u+4);
    }
  }
}

// ---------------- per-layer small mats: relself (601 rows) + q2e_vec (16 rows) ----------------
__global__ __launch_bounds__(256) void k_small(const float* rel_lin, const bf16* selfw,
    const bf16* selfb, const float* qnode, const bf16* q2ew, const bf16* q2eb,
    float* relself, float* q2ev){
  __shared__ float xr[DD];
  int d=threadIdx.x;
  if(blockIdx.x<601){
    int r=blockIdx.x;
    xr[d]=rel_lin[r*DD+d]; __syncthreads();
    float acc=b2f(selfb[d]);
    const bf16* wr=selfw+(long)d*DD;
    for(int k4=0;k4<DD;k4+=4){
      float v[4]; ld4bf(wr+k4,v);
      acc+=v[0]*xr[k4]+v[1]*xr[k4+1]+v[2]*xr[k4+2]+v[3]*xr[k4+3];
    }
    relself[r*DD+d]=acc;
  } else {
    int b=blockIdx.x-601;
    xr[d]=qnode[(b<<8)+d]; __syncthreads();
    float acc=b2f(q2eb[d]);
    const bf16* wr=q2ew+(long)d*DD;
    for(int k4=0;k4<DD;k4+=4){
      float v[4]; ld4bf(wr+k4,v);
      acc+=v[0]*xr[k4]+v[1]*xr[k4+1]+v[2]*xr[k4+2]+v[3]*xr[k4+3];
    }
    q2ev[(b<<8)+d]=acc;
  }
}

// ---------------- norm + scatter pagerank numerator ----------------
__global__ __launch_bounds__(256) void k_norm(const float* wt, const float* pr,
    const float* e2fs, const int* e2f, const int* f2e, float* normv, float* pragg){
  int i=blockIdx.x*256+threadIdx.x;
  int b=i>>13;
  int e=e2f[i];
  float v=wt[i]*pr[(b<<11)+e]/fmaxf(e2fs[(b<<11)+e],1e-10f);
  normv[i]=v;
  atomicAdd(pragg+(b<<11)+f2e[i], v);
}

__global__ __launch_bounds__(256) void k_f2e(const bf16* entself, const float* agg, bf16* f2eemb){
  long i4=((long)blockIdx.x*256+threadIdx.x)*4;
  float v[4]; ld4bf(entself+i4,v);
  float4 a=*(const float4*)(agg+i4);
  unsigned short u[4];
  bf16 t0=f2b(fmaxf(v[0]+a.x,0.f)); u[0]=*(unsigned short*)&t0;
  bf16 t1=f2b(fmaxf(v[1]+a.y,0.f)); u[1]=*(unsigned short*)&t1;
  bf16 t2=f2b(fmaxf(v[2]+a.z,0.f)); u[2]=*(unsigned short*)&t2;
  bf16 t3=f2b(fmaxf(v[3]+a.w,0.f)); u[3]=*(unsigned short*)&t3;
  *(short4*)(f2eemb+i4)=*(short4*)u;
}

__global__ __launch_bounds__(256) void k_prupd(const float* pragg, float* pr){
  int i4=(blockIdx.x*256+threadIdx.x)*4;
  float4 a=*(const float4*)(pragg+i4);
  float4 o=*(const float4*)(pr+i4);
  float4 r; r.x=0.8f*a.x+0.2f*o.x; r.y=0.8f*a.y+0.2f*o.y;
  r.z=0.8f*a.z+0.2f*o.z; r.w=0.8f*a.w+0.2f*o.w;
  *(float4*)(pr+i4)=r;
}

// ---------------- weighted row-sums (128 blocks, atomic partials) ----------------
__global__ __launch_bounds__(256) void k_wnxt(const float* pr, const bf16* le,
    const bf16* f2e, float* wnxt, float* prsum){
  int b=blockIdx.x, ch=blockIdx.y, d=threadIdx.x;
  float a1=0.f,a3=0.f,ap=0.f;
  int e0=ch*256;
  #pragma unroll 4
  for(int e=e0;e<e0+256;e++){
    float p=pr[(b<<11)+e];
    long base=(long)((b<<11)+e)<<8;
    a1+=p*b2f(le[base+d]);
    a3+=p*b2f(f2e[base+d]);
    ap+=p;
  }
  atomicAdd(&wnxt[b*768+d],a1);
  atomicAdd(&wnxt[b*768+512+d],a3);
  if(d==0) atomicAdd(&prsum[b],ap);
}

__global__ __launch_bounds__(256) void k_qnode(const float* wnxt, const float* prsum,
    const float* q2ev, const bf16* w, const bf16* bias, float* qnode){
  int b=blockIdx.x, d=threadIdx.x;
  __shared__ float xr[768];
  float ps=prsum[b];
  xr[d]=wnxt[b*768+d];
  xr[256+d]=ps*q2ev[(b<<8)+d];
  xr[512+d]=3.f*wnxt[b*768+512+d];
  __syncthreads();
  float acc=0.f;
  const bf16* wr=w+(long)d*768;
  for(int k4=0;k4<768;k4+=4){
    float v[4]; ld4bf(wr+k4,v);
    acc+=v[0]*xr[k4]+v[1]*xr[k4+1]+v[2]*xr[k4+2]+v[3]*xr[k4+3];
  }
  qnode[(b<<8)+d]=acc+ps*b2f(bias[d]);
}

// ---------------- score ----------------
__global__ __launch_bounds__(256) void k_score(const bf16* le, const bf16* sw,
    const bf16* sb, void* out, const int* dfl){
  const int isf=*dfl;
  int o=blockIdx.x*4 + (threadIdx.x>>6);
  int lane=threadIdx.x&63;
  float v[4],wv[4];
  ld4bf(le+(long)o*DD+lane*4,v); ld4bf(sw+lane*4,wv);
  float acc=v[0]*wv[0]+v[1]*wv[1]+v[2]*wv[2]+v[3]*wv[3];
  for(int off=32;off;off>>=1) acc+=__shfl_down(acc,off,64);
  if(!lane){
    float r=acc+b2f(sb[0]);
    if(isf) ((float*)out)[o]=r; else ((bf16*)out)[o]=f2b(r);
  }
}

// ---------------- host ----------------
extern "C" void kernel_launch(void* const* d_in, const int* in_sizes, int n_in,
                              void* d_out, int out_size, void* d_ws, size_t ws_size,
                              hipStream_t stream){
  const int*  local_entity=(const int*)d_in[0];
  const void* q2e_adj     =d_in[1];
  const int*  kb_fact_rel =(const int*)d_in[2];
  const int*  query_text  =(const int*)d_in[3];
  const int*  e2f_ent     =(const int*)d_in[5];
  const int*  f2e_ent     =(const int*)d_in[6];
  const void* word_emb    =d_in[7];
  const void* entity_emb  =d_in[8];
  const void* relation_emb=d_in[9];

  char* ws=(char*)d_ws;
  float* gx      =(float*)(ws+O_GX);
  float* qh      =(float*)(ws+O_QH);
  float* qnode   =(float*)(ws+O_QNODE);
  float* rel_lin =(float*)(ws+O_RELLIN);
  float* Wr      =(float*)(ws+O_WR);
  float* wmax    =(float*)(ws+O_WMAX);
  float* wt      =(float*)(ws+O_WT);
  float* e2fs    =(float*)(ws+O_E2FS);
  float* pr      =(float*)(ws+O_PR);
  float* pragg   =(float*)(ws+O_PRAGG);
  float* q2ev    =(float*)(ws+O_Q2EV);
  float* relself =(float*)(ws+O_RELSELF);
  float* normv   =(float*)(ws+O_NORM);
  float* wnxt    =(float*)(ws+O_WNXT);
  float* prsum   =(float*)(ws+O_PRSUM);
  float* f2eagg  =(float*)(ws+O_F2EAGG);
  bf16*  leA     =(bf16*)(ws+O_LEA);
  bf16*  leB     =(bf16*)(ws+O_LEB);
  bf16*  headb   =(bf16*)(ws+O_HEAD);
  bf16*  entself =(bf16*)(ws+O_ENTSELF);
  bf16*  f2eemb  =(bf16*)(ws+O_F2EEMB);
  int*   dflag   =(int*)(ws+O_FLAG);
  bf16*  cw      =(bf16*)(ws+O_CVT);

  k_sniff<<<1,256,0,stream>>>((const unsigned short*)entity_emb, dflag);

  // canonicalize all weights/biases to bf16
  CvtJobs J;
  int cnt=0;
  auto add=[&](int in_idx, long coff, int n){
    J.src[cnt]=d_in[in_idx]; J.dst[cnt]=cw+coff; J.n[cnt]=n; cnt++;
  };
  add(10,C_ELW,76800);   add(11,C_ELB,256);
  add(12,C_RLW,153600);  add(13,C_RLB,256);
  add(14,C_WIH,307200);  add(15,C_WHH,262144);
  add(16,C_BIH,1024);    add(17,C_BHH,1024);
  add(18,C_Q2EW,196608); add(19,C_Q2EB,768);
  add(20,C_E2QW,589824); add(21,C_E2QB,768);
  add(22,C_E2EW,589824); add(23,C_E2EB,768);
  add(24,C_KHW,196608);  add(25,C_KHB,768);
  add(26,C_KTW,196608);  add(27,C_KTB,768);
  add(28,C_KSW,196608);  add(29,C_KSB,768);
  add(30,C_SCW,256);     add(31,C_SCB,1);
  k_cvt<<<dim3(576,22),256,0,stream>>>(J, dflag);

  k_gx   <<<BB*QQ,256,0,stream>>>(query_text, word_emb, cw+C_WIH, cw+C_BIH, cw+C_BHH, gx, dflag);
  k_lstm <<<BB,1024,0,stream>>>(gx, cw+C_WHH, qh, qnode);
  k_rel_lin<<<601,256,0,stream>>>(relation_emb, cw+C_RLW, cw+C_RLB, rel_lin, dflag);
  k_simwr<<<dim3(BB,3),256,0,stream>>>(qh, rel_lin, query_text, Wr);
  k_wmax <<<BB,256,0,stream>>>(Wr, kb_fact_rel, wmax);
  hipMemsetAsync(e2fs, 0, (size_t)BB*EE*4, stream);
  k_wt   <<<BB*FF/256,256,0,stream>>>(Wr, kb_fact_rel, wmax, e2f_ent, wt, e2fs);
  k_prinit<<<BB*EE/1024,256,0,stream>>>(q2e_adj, pr, dflag);

  {
    GemmP p{}; p.M=BB*EE; p.K=WDIM; p.W=cw+C_ELW; p.bias=cw+C_ELB;
    p.idx=local_entity; p.emb=entity_emb; p.outb=leA; p.relu=0; p.dfl=dflag;
    k_gemm<0><<<dim3(BB*EE/128,2),256,0,stream>>>(p);
  }

  bf16* le_cur=leA; bf16* le_nxt=leB;
  for(int i=0;i<3;i++){
    k_small<<<617,256,0,stream>>>(rel_lin, cw+C_KSW+(long)i*65536, cw+C_KSB+(long)i*256,
        qnode, cw+C_Q2EW+(long)i*65536, cw+C_Q2EB+(long)i*256, relself, q2ev);
    {
      GemmP p{}; p.M=BB*EE; p.K=DD; p.W=cw+C_KHW+(long)i*65536; p.bias=cw+C_KHB+(long)i*256;
      p.Abf=le_cur; p.outb=headb; p.relu=0; p.dfl=dflag;
      k_gemm<1><<<dim3(BB*EE/128,2),256,0,stream>>>(p);
    }
    {
      GemmP p{}; p.M=BB*EE; p.K=DD; p.W=cw+C_KSW+(long)i*65536; p.bias=cw+C_KSB+(long)i*256;
      p.Abf=le_cur; p.outb=entself; p.relu=0; p.dfl=dflag;
      k_gemm<1><<<dim3(BB*EE/128,2),256,0,stream>>>(p);
    }
    hipMemsetAsync(f2eagg, 0, (size_t)BB*EE*DD*4, stream);
    hipMemsetAsync(pragg, 0, (size_t)BB*EE*4, stream);
    k_norm<<<BB*FF/256,256,0,stream>>>(wt, pr, e2fs, e2f_ent, f2e_ent, normv, pragg);
    {
      GemmP p{}; p.M=BB*FF; p.K=DD; p.W=cw+C_KTW+(long)i*65536; p.bias=cw+C_KTB+(long)i*256;
      p.relself=relself; p.rel=kb_fact_rel; p.e2f=e2f_ent; p.normv=normv; p.headb=headb;
      p.outat=f2eagg; p.f2e=f2e_ent; p.dfl=dflag;
      k_gemm<2><<<dim3(BB*FF/128,2),256,0,stream>>>(p);
    }
    k_f2e  <<<BB*EE*DD/1024,256,0,stream>>>(entself, f2eagg, f2eemb);
    k_prupd<<<BB*EE/1024,256,0,stream>>>(pragg, pr);
    hipMemsetAsync(wnxt, 0, (size_t)(BB*768*4+64), stream);
    k_wnxt <<<dim3(BB,8),256,0,stream>>>(pr, le_cur, f2eemb, wnxt, prsum);
    k_qnode<<<BB,256,0,stream>>>(wnxt, prsum, q2ev, cw+C_E2QW+(long)i*196608, cw+C_E2QB+(long)i*256, qnode);
    {
      GemmP p{}; p.M=BB*EE; p.K=768; p.W=cw+C_E2EW+(long)i*196608; p.bias=cw+C_E2EB+(long)i*256;
      p.Abf=le_cur; p.q2ev=q2ev; p.f2eb=f2eemb; p.outb=le_nxt; p.relu=1; p.dfl=dflag;
      k_gemm<3><<<dim3(BB*EE/128,2),256,0,stream>>>(p);
    }
    bf16* t=le_cur; le_cur=le_nxt; le_nxt=t;
  }

  k_score<<<BB*EE/4,256,0,stream>>>(le_cur, cw+C_SCW, cw+C_SCB, d_out, dflag);
}

// Round 4
// 1397.493 us; speedup vs baseline: 5.1566x; 3.3085x over previous
//
#include <hip/hip_runtime.h>
#include <hip/hip_bf16.h>

typedef __hip_bfloat16 bf16;
typedef __attribute__((ext_vector_type(8))) short bf16x8;
typedef __attribute__((ext_vector_type(4))) float f32x4;

#define BB 16
#define EE 2048
#define FF 8192
#define QQ 20
#define DD 256
#define WDIM 300
#define NWORD 50000
#define VERY_NEG_F (-1.0e11f)

static __device__ __forceinline__ float b2f(bf16 x){ return __bfloat162float(x); }
static __device__ __forceinline__ bf16 f2b(float x){ return __float2bfloat16(x); }
static __device__ __forceinline__ float sigm(float x){ return 1.f/(1.f+expf(-x)); }
static __device__ __forceinline__ void ld4bf(const bf16* p, float v[4]){
  short4 s = *(const short4*)p;
  v[0]=b2f(*(const bf16*)&s.x); v[1]=b2f(*(const bf16*)&s.y);
  v[2]=b2f(*(const bf16*)&s.z); v[3]=b2f(*(const bf16*)&s.w);
}
static __device__ __forceinline__ void st4bf(bf16* p, float a,float b,float c,float d){
  unsigned short u[4]; bf16 t;
  t=f2b(a);u[0]=*(unsigned short*)&t; t=f2b(b);u[1]=*(unsigned short*)&t;
  t=f2b(c);u[2]=*(unsigned short*)&t; t=f2b(d);u[3]=*(unsigned short*)&t;
  *(short4*)p=*(short4*)u;
}

// ---------------- workspace offsets (bytes) ----------------
#define O_GX       0UL
#define O_QH       1310720UL
#define O_QNODE    1638400UL
#define O_RELLIN   1654784UL
#define O_WR       2270208UL
#define O_WMAX     2308864UL
#define O_WT       2309120UL
#define O_E2FS     2833408UL
#define O_PR       2964480UL
#define O_PRAGG    3095552UL
#define O_Q2EV     3226624UL
#define O_Q2EVB    3243008UL
#define O_RELSELF  3251200UL
#define O_NORM     3866624UL
#define O_WNXT     4390912UL
#define O_PRSUM    4440064UL
#define O_CNT      4440320UL
#define O_CUR      4571392UL
#define O_BSTART   4702464UL
#define O_BIDX     4834048UL
#define O_ELWPAD   5358336UL
#define O_FLAG     5522176UL
#define O_CVT      5522432UL   // 5393152 B
#define O_AGG      10915584UL  // bf16 16.7MB; A0 (21MB) aliases AGG+start of ENTSELF
#define O_ENTSELF  27692800UL
#define O_LEA      44470016UL
#define O_LEB      61247232UL
#define O_HEAD     78024448UL
#define O_F2EEMB   94801664UL  // end ~111.6MB

// canonical element offsets within O_CVT (all mult of 8)
#define C_ELB   0
#define C_RLW   256
#define C_RLB   153856
#define C_WIH   154112
#define C_WHH   461312
#define C_BIH   723456
#define C_BHH   724480
#define C_Q2EW  725504
#define C_Q2EB  922112
#define C_E2QW  922880
#define C_E2QB  1512704
#define C_E2EW  1513472
#define C_E2EB  2103296
#define C_KHW   2104064
#define C_KHB   2300672
#define C_KTW   2301440
#define C_KTB   2498048
#define C_KSW   2498816
#define C_KSB   2695424
#define C_SCW   2696192
#define C_SCB   2696448

// ---------------- dtype sniffer (verified r2) ----------------
__global__ __launch_bounds__(256) void k_sniff(const unsigned short* ee, int* flag){
  __shared__ int red[256];
  int c=0;
  for(int i=threadIdx.x;i<4096;i+=256){
    int ex=(ee[2*i]>>7)&0xFF;
    c += (ex>=192);
  }
  red[threadIdx.x]=c; __syncthreads();
  for(int o=128;o;o>>=1){ if(threadIdx.x<o) red[threadIdx.x]+=red[threadIdx.x+o]; __syncthreads(); }
  if(!threadIdx.x) flag[0] = (red[0]>64) ? 1 : 0;
}

// ---------------- batched weight canonicalization -> bf16 (tail-scale for e2q/e2e) ----------------
struct CvtJobs{ const void* src[21]; bf16* dst[21]; int n[21]; int sc[21]; };
__global__ __launch_bounds__(256) void k_cvt(CvtJobs J, const int* dfl){
  const int isf=*dfl;
  int j=blockIdx.y;
  int n=J.n[j];
  int i4=(blockIdx.x*256+threadIdx.x)*4;
  if(i4>=n) return;
  float m = (J.sc[j] && ((i4%768)>=512)) ? 3.f : 1.f;
  bf16* d=J.dst[j]+i4;
  if(isf){
    const float* s=(const float*)J.src[j]+i4;
    if(i4+4<=n){ float4 t=*(const float4*)s; st4bf(d,t.x*m,t.y*m,t.z*m,t.w*m); }
    else for(int r=0;i4+r<n;r++) d[r]=f2b(s[r]*m);
  } else {
    const bf16* s=(const bf16*)J.src[j]+i4;
    if(i4+4<=n){ float v[4]; ld4bf(s,v); st4bf(d,v[0]*m,v[1]*m,v[2]*m,v[3]*m); }
    else for(int r=0;i4+r<n;r++) d[r]=f2b(b2f(s[r])*m);
  }
}

// entity_lin_w (256x300) -> padded bf16 (256x320)
__global__ __launch_bounds__(256) void k_cvtelw(const void* src, bf16* dst, const int* dfl){
  const int isf=*dfl;
  int r=blockIdx.x;
  for(int c=threadIdx.x;c<320;c+=256){
    float v=0.f;
    if(c<300) v = isf ? ((const float*)src)[r*300+c] : b2f(((const bf16*)src)[r*300+c]);
    dst[(long)r*320+c]=f2b(v);
  }
}

// gathered, padded A0[32768][320] = entity_emb[local_entity]
__global__ __launch_bounds__(128) void k_ga0(const int* idx, const void* emb, bf16* A0, const int* dfl){
  const int isf=*dfl;
  int row=blockIdx.x; int ent=idx[row]; int t=threadIdx.x;
  bf16* dst=A0+(long)row*320;
  if(t<75){
    float v[4];
    if(isf){ float4 x=*(const float4*)((const float*)emb+(long)ent*WDIM+t*4);
             v[0]=x.x;v[1]=x.y;v[2]=x.z;v[3]=x.w; }
    else ld4bf((const bf16*)emb+(long)ent*WDIM+t*4, v);
    st4bf(dst+t*4, v[0],v[1],v[2],v[3]);
  } else if(t<80){
    st4bf(dst+t*4, 0.f,0.f,0.f,0.f);
  }
}

// ---------------- CSR bucketing of facts by (b, f2e_ent) ----------------
__global__ __launch_bounds__(256) void k_cnt(const int* f2e, int* cnt){
  int i=blockIdx.x*256+threadIdx.x;
  atomicAdd(&cnt[((i>>13)<<11)+f2e[i]], 1);
}
__global__ __launch_bounds__(1024) void k_scan(const int* cnt, int* bstart){
  __shared__ int ps[1024];
  int t=threadIdx.x;
  int loc[32]; int s=0;
  #pragma unroll
  for(int j=0;j<32;j++){ loc[j]=s; s+=cnt[t*32+j]; }
  ps[t]=s; __syncthreads();
  for(int off=1;off<1024;off<<=1){
    int v=(t>=off)?ps[t-off]:0;
    __syncthreads(); ps[t]+=v; __syncthreads();
  }
  int base=(t? ps[t-1]:0);
  #pragma unroll
  for(int j=0;j<32;j++) bstart[t*32+j]=base+loc[j];
  if(t==1023) bstart[32768]=ps[1023];
}
__global__ __launch_bounds__(256) void k_fill(const int* f2e, const int* bstart, int* cur, int* bidx){
  int i=blockIdx.x*256+threadIdx.x;
  int key=((i>>13)<<11)+f2e[i];
  int pos=bstart[key]+atomicAdd(&cur[key],1);
  bidx[pos]=i;
}

// ---------------- gx = wemb[qtext] @ w_ih^T + b_ih + b_hh ----------------
__global__ __launch_bounds__(256) void k_gx(const int* qtext, const void* wemb,
    const bf16* wih, const bf16* bih, const bf16* bhh, float* gx, const int* dfl){
  const int isf=*dfl;
  int bt=blockIdx.x;
  __shared__ float xr[WDIM];
  int w=qtext[bt];
  for(int k4=threadIdx.x*4;k4<WDIM;k4+=1024){
    if(isf){ float4 t=*(const float4*)((const float*)wemb+(long)w*WDIM+k4);
             xr[k4]=t.x;xr[k4+1]=t.y;xr[k4+2]=t.z;xr[k4+3]=t.w; }
    else   { float v[4]; ld4bf((const bf16*)wemb+(long)w*WDIM+k4,v);
             xr[k4]=v[0];xr[k4+1]=v[1];xr[k4+2]=v[2];xr[k4+3]=v[3]; }
  }
  __syncthreads();
  #pragma unroll
  for(int s=0;s<4;s++){
    int g=threadIdx.x+256*s;
    float acc=b2f(bih[g])+b2f(bhh[g]);
    const bf16* wr=wih+(long)g*WDIM;
    for(int k4=0;k4<WDIM;k4+=4){
      float v[4]; ld4bf(wr+k4,v);
      acc+=v[0]*xr[k4]+v[1]*xr[k4+1]+v[2]*xr[k4+2]+v[3]*xr[k4+3];
    }
    gx[bt*1024+g]=acc;
  }
}

// ---------------- LSTM recurrence ----------------
__global__ __launch_bounds__(1024) void k_lstm(const float* gx, const bf16* whh,
    float* qh, float* qnode){
  int b = blockIdx.x;
  __shared__ float h[DD], c[DD], z[4*DD];
  int tid = threadIdx.x;
  if(tid<DD){ h[tid]=0.f; c[tid]=0.f; }
  __syncthreads();
  const bf16* wr = whh + (long)tid*DD;
  for(int t=0;t<QQ;t++){
    float acc = gx[(b*QQ+t)*1024 + tid];
    #pragma unroll 8
    for(int j=0;j<64;j++){
      float w[4]; ld4bf(wr+j*4,w);
      float4 hv=*(const float4*)&h[j*4];
      acc += w[0]*hv.x+w[1]*hv.y+w[2]*hv.z+w[3]*hv.w;
    }
    z[tid]=acc;
    __syncthreads();
    if(tid<DD){
      float zi=z[tid], zf=z[DD+tid], zg=z[2*DD+tid], zo=z[3*DD+tid];
      float ci = sigm(zf)*c[tid] + sigm(zi)*tanhf(zg);
      c[tid]=ci;
      float hh = sigm(zo)*tanhf(ci);
      h[tid]=hh;
      qh[(b*QQ+t)*DD+tid]=hh;
    }
    __syncthreads();
  }
  if(tid<DD) qnode[b*DD+tid]=h[tid];
}

// ---------------- rel_lin ----------------
__global__ __launch_bounds__(256) void k_rel_lin(const void* remb, const bf16* rlw,
    const bf16* rlb, float* rel_lin, const int* dfl){
  const int isf=*dfl;
  int r=blockIdx.x;
  __shared__ float rr[2*WDIM];
  for(int k4=threadIdx.x*4;k4<2*WDIM;k4+=1024){
    if(isf){ float4 t=*(const float4*)((const float*)remb+(long)r*2*WDIM+k4);
             rr[k4]=t.x;rr[k4+1]=t.y;rr[k4+2]=t.z;rr[k4+3]=t.w; }
    else   { float v[4]; ld4bf((const bf16*)remb+(long)r*2*WDIM+k4,v);
             rr[k4]=v[0];rr[k4+1]=v[1];rr[k4+2]=v[2];rr[k4+3]=v[3]; }
  }
  __syncthreads();
  int d=threadIdx.x;
  float acc=b2f(rlb[d]);
  const bf16* wr=rlw+(long)d*2*WDIM;
  for(int k4=0;k4<2*WDIM;k4+=4){
    float v[4]; ld4bf(wr+k4,v);
    acc+=v[0]*rr[k4]+v[1]*rr[k4+1]+v[2]*rr[k4+2]+v[3]*rr[k4+3];
  }
  rel_lin[r*DD+d]=acc;
}

// ---------------- sim + masked softmax + Wr (relation space) ----------------
__global__ __launch_bounds__(256) void k_simwr(const float* qh, const float* rel_lin,
    const int* qtext, float* Wr){
  int b = blockIdx.x, rc = blockIdx.y;
  __shared__ float qhb[QQ*DD];
  __shared__ float qm[QQ];
  for(int i=threadIdx.x;i<QQ*DD;i+=256) qhb[i]=qh[b*QQ*DD+i];
  if(threadIdx.x<QQ) qm[threadIdx.x] = (qtext[b*QQ+threadIdx.x]!=NWORD)?0.f:VERY_NEG_F;
  __syncthreads();
  int r = rc*256+threadIdx.x;
  if(r>=601) return;
  float s[QQ];
  #pragma unroll
  for(int q=0;q<QQ;q++) s[q]=0.f;
  for(int k=0;k<DD;k++){
    float rl = rel_lin[r*DD+k];
    #pragma unroll
    for(int q=0;q<QQ;q++) s[q] += qhb[q*DD+k]*rl;
  }
  float m=-1e30f;
  #pragma unroll
  for(int q=0;q<QQ;q++){ s[q]*=0.0625f; m=fmaxf(m, s[q]+qm[q]); }
  float sum=0.f, w=0.f;
  #pragma unroll
  for(int q=0;q<QQ;q++){ float p=expf(s[q]+qm[q]-m); sum+=p; w+=p*s[q]; }
  Wr[b*601+r] = w/sum;
}

// ---------------- Wmax / W_tilde / e2f_softmax / pr init ----------------
__global__ __launch_bounds__(256) void k_wmax(const float* Wr, const int* rel, float* wmax){
  int b=blockIdx.x; __shared__ float red[256];
  float m=-1e30f;
  for(int f=threadIdx.x;f<FF;f+=256) m=fmaxf(m, Wr[b*601+rel[b*FF+f]]);
  red[threadIdx.x]=m; __syncthreads();
  for(int o=128;o;o>>=1){ if(threadIdx.x<o) red[threadIdx.x]=fmaxf(red[threadIdx.x],red[threadIdx.x+o]); __syncthreads(); }
  if(!threadIdx.x) wmax[b]=red[0];
}
__global__ __launch_bounds__(256) void k_wt(const float* Wr, const int* rel,
    const float* wmax, const int* e2f, float* wt, float* e2fs){
  int i = blockIdx.x*256+threadIdx.x;
  int b = i>>13;
  float v = expf(Wr[b*601+rel[i]] - wmax[b]);
  wt[i]=v;
  atomicAdd(e2fs + (b<<11) + e2f[i], v);
}
__global__ __launch_bounds__(256) void k_prinit(const void* adj, float* pr, const int* dfl){
  const int isf=*dfl;
  int i4=(blockIdx.x*256+threadIdx.x)*4;
  if(isf){ *(float4*)(pr+i4)=*(const float4*)((const float*)adj+i4); }
  else { float v[4]; ld4bf((const bf16*)adj+i4,v);
         float4 t; t.x=v[0];t.y=v[1];t.z=v[2];t.w=v[3]; *(float4*)(pr+i4)=t; }
}

// ---------------- MFMA GEMM: C[M,256] = A[M,K] @ W[256,K]^T, no LDS ----------------
// CONCAT: A = [le | q2evb(bcast b) | f2eemb], K=768 (tail-scale folded into W)
// EPI 0: +bias; 1: relu(+bias); 2: relu(acc + cnt*bias + addb_row)
struct MG {
  const bf16* A; const bf16* W; const bf16* bias;
  bf16* out; int K;
  const bf16* Aq2; const bf16* Af2;
  const int* cnt; const bf16* addb;
};
template<int CONCAT,int EPI>
__global__ __launch_bounds__(256) void k_mgemm(MG p){
  const int m0 = blockIdx.x*64;
  const int wave = threadIdx.x>>6, lane = threadIdx.x&63;
  const int q = lane>>4, l16 = lane&15;
  const int n0 = wave*64;
  const int bidx_ = m0>>11;
  f32x4 acc[4][4];
  #pragma unroll
  for(int i=0;i<4;i++)
    #pragma unroll
    for(int j=0;j<4;j++) acc[i][j]=(f32x4){0.f,0.f,0.f,0.f};
  const int K=p.K;
  for(int k0=0;k0<K;k0+=32){
    int kk=k0+q*8;
    bf16x8 af[4], bw[4];
    #pragma unroll
    for(int mi=0;mi<4;mi++){
      int row=m0+mi*16+l16;
      const bf16* ap;
      if(CONCAT){
        if(kk<256)      ap=p.A  +(long)row*256+kk;
        else if(kk<512) ap=p.Aq2+(bidx_<<8)+(kk-256);
        else            ap=p.Af2+(long)row*256+(kk-512);
      } else ap=p.A+(long)row*K+kk;
      af[mi]=*(const bf16x8*)ap;
    }
    #pragma unroll
    for(int ni=0;ni<4;ni++)
      bw[ni]=*(const bf16x8*)(p.W+(long)(n0+ni*16+l16)*K+kk);
    #pragma unroll
    for(int mi=0;mi<4;mi++)
      #pragma unroll
      for(int ni=0;ni<4;ni++)
        acc[mi][ni]=__builtin_amdgcn_mfma_f32_16x16x32_bf16(af[mi],bw[ni],acc[mi][ni],0,0,0);
  }
  #pragma unroll
  for(int ni=0;ni<4;ni++){
    int col=n0+ni*16+l16;
    float bv=b2f(p.bias[col]);
    #pragma unroll
    for(int mi=0;mi<4;mi++){
      #pragma unroll
      for(int r=0;r<4;r++){
        int row=m0+mi*16+q*4+r;
        float v=acc[mi][ni][r];
        if(EPI==0) v+=bv;
        else if(EPI==1) v=fmaxf(v+bv,0.f);
        else {
          v += (float)p.cnt[row]*bv + b2f(p.addb[(long)row*256+col]);
          v=fmaxf(v,0.f);
        }
        p.out[(long)row*256+col]=f2b(v);
      }
    }
  }
}

// ---------------- per-layer small mats ----------------
__global__ __launch_bounds__(256) void k_small(const float* rel_lin, const bf16* selfw,
    const bf16* selfb, const float* qnode, const bf16* q2ew, const bf16* q2eb,
    float* relself, float* q2ev, bf16* q2evb){
  __shared__ float xr[DD];
  int d=threadIdx.x;
  if(blockIdx.x<601){
    int r=blockIdx.x;
    xr[d]=rel_lin[r*DD+d]; __syncthreads();
    float acc=b2f(selfb[d]);
    const bf16* wr=selfw+(long)d*DD;
    for(int k4=0;k4<DD;k4+=4){
      float v[4]; ld4bf(wr+k4,v);
      acc+=v[0]*xr[k4]+v[1]*xr[k4+1]+v[2]*xr[k4+2]+v[3]*xr[k4+3];
    }
    relself[r*DD+d]=acc;
  } else {
    int b=blockIdx.x-601;
    xr[d]=qnode[(b<<8)+d]; __syncthreads();
    float acc=b2f(q2eb[d]);
    const bf16* wr=q2ew+(long)d*DD;
    for(int k4=0;k4<DD;k4+=4){
      float v[4]; ld4bf(wr+k4,v);
      acc+=v[0]*xr[k4]+v[1]*xr[k4+1]+v[2]*xr[k4+2]+v[3]*xr[k4+3];
    }
    q2ev[(b<<8)+d]=acc;
    q2evb[(b<<8)+d]=f2b(acc);
  }
}

// ---------------- norm + pagerank numerator scatter ----------------
__global__ __launch_bounds__(256) void k_norm(const float* wt, const float* pr,
    const float* e2fs, const int* e2f, const int* f2e, float* normv, float* pragg){
  int i=blockIdx.x*256+threadIdx.x;
  int b=i>>13;
  int e=e2f[i];
  float v=wt[i]*pr[(b<<11)+e]/fmaxf(e2fs[(b<<11)+e],1e-10f);
  normv[i]=v;
  atomicAdd(pragg+(b<<11)+f2e[i], v);
}

// ---------------- segmented fact aggregation (atomic-free) ----------------
__global__ __launch_bounds__(256) void k_agg(const int* bstart, const int* bidx,
    const int* rel, const int* e2f, const float* normv, const float* relself,
    const bf16* head, bf16* agg){
  int eidx=blockIdx.x*4+(threadIdx.x>>6);
  int lane=threadIdx.x&63;
  int b=eidx>>11;
  float a0=0.f,a1=0.f,a2=0.f,a3=0.f;
  int s=bstart[eidx], e=bstart[eidx+1];
  for(int i=s;i<e;i++){
    int f=bidx[i];
    int r=rel[f]; int ent=e2f[f]; float nv=normv[f];
    float4 rs=*(const float4*)&relself[r*DD+lane*4];
    float hd[4]; ld4bf(head+(long)(((b<<11)+ent)*DD+lane*4),hd);
    a0+=fmaxf(rs.x+hd[0],0.f)*nv; a1+=fmaxf(rs.y+hd[1],0.f)*nv;
    a2+=fmaxf(rs.z+hd[2],0.f)*nv; a3+=fmaxf(rs.w+hd[3],0.f)*nv;
  }
  st4bf(agg+(long)eidx*DD+lane*4, a0,a1,a2,a3);
}

__global__ __launch_bounds__(256) void k_prupd(const float* pragg, float* pr){
  int i4=(blockIdx.x*256+threadIdx.x)*4;
  float4 a=*(const float4*)(pragg+i4);
  float4 o=*(const float4*)(pr+i4);
  float4 r; r.x=0.8f*a.x+0.2f*o.x; r.y=0.8f*a.y+0.2f*o.y;
  r.z=0.8f*a.z+0.2f*o.z; r.w=0.8f*a.w+0.2f*o.w;
  *(float4*)(pr+i4)=r;
}

// ---------------- weighted row-sums ----------------
__global__ __launch_bounds__(256) void k_wnxt(const float* pr, const bf16* le,
    const bf16* f2e, float* wnxt, float* prsum){
  int b=blockIdx.x, ch=blockIdx.y, d=threadIdx.x;
  float a1=0.f,a3=0.f,ap=0.f;
  int e0=ch*256;
  #pragma unroll 4
  for(int e=e0;e<e0+256;e++){
    float p=pr[(b<<11)+e];
    long base=(long)((b<<11)+e)<<8;
    a1+=p*b2f(le[base+d]);
    a3+=p*b2f(f2e[base+d]);
    ap+=p;
  }
  atomicAdd(&wnxt[b*768+d],a1);
  atomicAdd(&wnxt[b*768+512+d],a3);
  if(d==0) atomicAdd(&prsum[b],ap);
}

// note: e2q_w tail cols pre-scaled by 3 at cvt -> xr segment 3 is plain a3
__global__ __launch_bounds__(256) void k_qnode(const float* wnxt, const float* prsum,
    const float* q2ev, const bf16* w, const bf16* bias, float* qnode){
  int b=blockIdx.x, d=threadIdx.x;
  __shared__ float xr[768];
  float ps=prsum[b];
  xr[d]=wnxt[b*768+d];
  xr[256+d]=ps*q2ev[(b<<8)+d];
  xr[512+d]=wnxt[b*768+512+d];
  __syncthreads();
  float acc=0.f;
  const bf16* wr=w+(long)d*768;
  for(int k4=0;k4<768;k4+=4){
    float v[4]; ld4bf(wr+k4,v);
    acc+=v[0]*xr[k4]+v[1]*xr[k4+1]+v[2]*xr[k4+2]+v[3]*xr[k4+3];
  }
  qnode[(b<<8)+d]=acc+ps*b2f(bias[d]);
}

// ---------------- score ----------------
__global__ __launch_bounds__(256) void k_score(const bf16* le, const bf16* sw,
    const bf16* sb, void* out, const int* dfl){
  const int isf=*dfl;
  int o=blockIdx.x*4 + (threadIdx.x>>6);
  int lane=threadIdx.x&63;
  float v[4],wv[4];
  ld4bf(le+(long)o*DD+lane*4,v); ld4bf(sw+lane*4,wv);
  float acc=v[0]*wv[0]+v[1]*wv[1]+v[2]*wv[2]+v[3]*wv[3];
  for(int off=32;off;off>>=1) acc+=__shfl_down(acc,off,64);
  if(!lane){
    float r=acc+b2f(sb[0]);
    if(isf) ((float*)out)[o]=r; else ((bf16*)out)[o]=f2b(r);
  }
}

// ---------------- host ----------------
extern "C" void kernel_launch(void* const* d_in, const int* in_sizes, int n_in,
                              void* d_out, int out_size, void* d_ws, size_t ws_size,
                              hipStream_t stream){
  const int*  local_entity=(const int*)d_in[0];
  const void* q2e_adj     =d_in[1];
  const int*  kb_fact_rel =(const int*)d_in[2];
  const int*  query_text  =(const int*)d_in[3];
  const int*  e2f_ent     =(const int*)d_in[5];
  const int*  f2e_ent     =(const int*)d_in[6];
  const void* word_emb    =d_in[7];
  const void* entity_emb  =d_in[8];
  const void* relation_emb=d_in[9];

  char* ws=(char*)d_ws;
  float* gx      =(float*)(ws+O_GX);
  float* qh      =(float*)(ws+O_QH);
  float* qnode   =(float*)(ws+O_QNODE);
  float* rel_lin =(float*)(ws+O_RELLIN);
  float* Wr      =(float*)(ws+O_WR);
  float* wmax    =(float*)(ws+O_WMAX);
  float* wt      =(float*)(ws+O_WT);
  float* e2fs    =(float*)(ws+O_E2FS);
  float* pr      =(float*)(ws+O_PR);
  float* pragg   =(float*)(ws+O_PRAGG);
  float* q2ev    =(float*)(ws+O_Q2EV);
  bf16*  q2evb   =(bf16*)(ws+O_Q2EVB);
  float* relself =(float*)(ws+O_RELSELF);
  float* normv   =(float*)(ws+O_NORM);
  float* wnxt    =(float*)(ws+O_WNXT);
  float* prsum   =(float*)(ws+O_PRSUM);
  int*   cnt     =(int*)(ws+O_CNT);
  int*   cur     =(int*)(ws+O_CUR);
  int*   bstart  =(int*)(ws+O_BSTART);
  int*   bidx    =(int*)(ws+O_BIDX);
  bf16*  elwpad  =(bf16*)(ws+O_ELWPAD);
  int*   dflag   =(int*)(ws+O_FLAG);
  bf16*  cw      =(bf16*)(ws+O_CVT);
  bf16*  agg     =(bf16*)(ws+O_AGG);
  bf16*  A0      =(bf16*)(ws+O_AGG);      // aliases agg + start of entself (pre-layer use only)
  bf16*  entself =(bf16*)(ws+O_ENTSELF);
  bf16*  leA     =(bf16*)(ws+O_LEA);
  bf16*  leB     =(bf16*)(ws+O_LEB);
  bf16*  headb   =(bf16*)(ws+O_HEAD);
  bf16*  f2eemb  =(bf16*)(ws+O_F2EEMB);

  k_sniff<<<1,256,0,stream>>>((const unsigned short*)entity_emb, dflag);

  CvtJobs J;
  int cntj=0;
  auto add=[&](int in_idx, long coff, int n, int sc){
    J.src[cntj]=d_in[in_idx]; J.dst[cntj]=cw+coff; J.n[cntj]=n; J.sc[cntj]=sc; cntj++;
  };
  add(11,C_ELB,256,0);
  add(12,C_RLW,153600,0);  add(13,C_RLB,256,0);
  add(14,C_WIH,307200,0);  add(15,C_WHH,262144,0);
  add(16,C_BIH,1024,0);    add(17,C_BHH,1024,0);
  add(18,C_Q2EW,196608,0); add(19,C_Q2EB,768,0);
  add(20,C_E2QW,589824,1); add(21,C_E2QB,768,0);
  add(22,C_E2EW,589824,1); add(23,C_E2EB,768,0);
  add(24,C_KHW,196608,0);  add(25,C_KHB,768,0);
  add(26,C_KTW,196608,0);  add(27,C_KTB,768,0);
  add(28,C_KSW,196608,0);  add(29,C_KSB,768,0);
  add(30,C_SCW,256,0);     add(31,C_SCB,1,0);
  k_cvt<<<dim3(576,21),256,0,stream>>>(J, dflag);
  k_cvtelw<<<256,256,0,stream>>>(d_in[10], elwpad, dflag);

  // CSR bucketing (fact graph is launch-constant)
  hipMemsetAsync(cnt, 0, (size_t)BB*EE*4, stream);
  hipMemsetAsync(cur, 0, (size_t)BB*EE*4, stream);
  k_cnt <<<BB*FF/256,256,0,stream>>>(f2e_ent, cnt);
  k_scan<<<1,1024,0,stream>>>(cnt, bstart);
  k_fill<<<BB*FF/256,256,0,stream>>>(f2e_ent, bstart, cur, bidx);

  k_gx   <<<BB*QQ,256,0,stream>>>(query_text, word_emb, cw+C_WIH, cw+C_BIH, cw+C_BHH, gx, dflag);
  k_lstm <<<BB,1024,0,stream>>>(gx, cw+C_WHH, qh, qnode);
  k_rel_lin<<<601,256,0,stream>>>(relation_emb, cw+C_RLW, cw+C_RLB, rel_lin, dflag);
  k_simwr<<<dim3(BB,3),256,0,stream>>>(qh, rel_lin, query_text, Wr);
  k_wmax <<<BB,256,0,stream>>>(Wr, kb_fact_rel, wmax);
  hipMemsetAsync(e2fs, 0, (size_t)BB*EE*4, stream);
  k_wt   <<<BB*FF/256,256,0,stream>>>(Wr, kb_fact_rel, wmax, e2f_ent, wt, e2fs);
  k_prinit<<<BB*EE/1024,256,0,stream>>>(q2e_adj, pr, dflag);

  // le = entity_emb[local_entity] @ elw^T + elb   (K padded to 320)
  k_ga0<<<BB*EE,128,0,stream>>>(local_entity, entity_emb, A0, dflag);
  {
    MG p{}; p.A=A0; p.W=elwpad; p.bias=cw+C_ELB; p.out=leA; p.K=320;
    k_mgemm<0,0><<<BB*EE/64,256,0,stream>>>(p);
  }

  bf16* le_cur=leA; bf16* le_nxt=leB;
  for(int i=0;i<3;i++){
    k_small<<<617,256,0,stream>>>(rel_lin, cw+C_KSW+(long)i*65536, cw+C_KSB+(long)i*256,
        qnode, cw+C_Q2EW+(long)i*65536, cw+C_Q2EB+(long)i*256, relself, q2ev, q2evb);
    {
      MG p{}; p.A=le_cur; p.W=cw+C_KHW+(long)i*65536; p.bias=cw+C_KHB+(long)i*256;
      p.out=headb; p.K=256;
      k_mgemm<0,0><<<BB*EE/64,256,0,stream>>>(p);
    }
    {
      MG p{}; p.A=le_cur; p.W=cw+C_KSW+(long)i*65536; p.bias=cw+C_KSB+(long)i*256;
      p.out=entself; p.K=256;
      k_mgemm<0,0><<<BB*EE/64,256,0,stream>>>(p);
    }
    hipMemsetAsync(pragg, 0, (size_t)BB*EE*4, stream);
    k_norm<<<BB*FF/256,256,0,stream>>>(wt, pr, e2fs, e2f_ent, f2e_ent, normv, pragg);
    k_agg <<<BB*EE/4,256,0,stream>>>(bstart, bidx, kb_fact_rel, e2f_ent, normv, relself, headb, agg);
    {
      MG p{}; p.A=agg; p.W=cw+C_KTW+(long)i*65536; p.bias=cw+C_KTB+(long)i*256;
      p.out=f2eemb; p.K=256; p.cnt=cnt; p.addb=entself;
      k_mgemm<0,2><<<BB*EE/64,256,0,stream>>>(p);
    }
    k_prupd<<<BB*EE/1024,256,0,stream>>>(pragg, pr);
    hipMemsetAsync(wnxt, 0, (size_t)(BB*768*4+256), stream);
    k_wnxt <<<dim3(BB,8),256,0,stream>>>(pr, le_cur, f2eemb, wnxt, prsum);
    k_qnode<<<BB,256,0,stream>>>(wnxt, prsum, q2ev, cw+C_E2QW+(long)i*196608, cw+C_E2QB+(long)i*256, qnode);
    {
      MG p{}; p.A=le_cur; p.W=cw+C_E2EW+(long)i*196608; p.bias=cw+C_E2EB+(long)i*256;
      p.out=le_nxt; p.K=768; p.Aq2=q2evb; p.Af2=f2eemb;
      k_mgemm<1,1><<<BB*EE/64,256,0,stream>>>(p);
    }
    bf16* t=le_cur; le_cur=le_nxt; le_nxt=t;
  }

  k_score<<<BB*EE/4,256,0,stream>>>(le_cur, cw+C_SCW, cw+C_SCB, d_out, dflag);
}

// Round 5
// 1397.220 us; speedup vs baseline: 5.1577x; 1.0002x over previous
//
#include <hip/hip_runtime.h>
#include <hip/hip_bf16.h>

typedef __hip_bfloat16 bf16;
typedef __attribute__((ext_vector_type(8))) short bf16x8;
typedef __attribute__((ext_vector_type(4))) float f32x4;

#define BB 16
#define EE 2048
#define FF 8192
#define QQ 20
#define DD 256
#define WDIM 300
#define NWORD 50000
#define VERY_NEG_F (-1.0e11f)

static __device__ __forceinline__ float b2f(bf16 x){ return __bfloat162float(x); }
static __device__ __forceinline__ bf16 f2b(float x){ return __float2bfloat16(x); }
static __device__ __forceinline__ float sigm(float x){ return 1.f/(1.f+expf(-x)); }
static __device__ __forceinline__ void ld4bf(const bf16* p, float v[4]){
  short4 s = *(const short4*)p;
  v[0]=b2f(*(const bf16*)&s.x); v[1]=b2f(*(const bf16*)&s.y);
  v[2]=b2f(*(const bf16*)&s.z); v[3]=b2f(*(const bf16*)&s.w);
}
static __device__ __forceinline__ void st4bf(bf16* p, float a,float b,float c,float d){
  unsigned short u[4]; bf16 t;
  t=f2b(a);u[0]=*(unsigned short*)&t; t=f2b(b);u[1]=*(unsigned short*)&t;
  t=f2b(c);u[2]=*(unsigned short*)&t; t=f2b(d);u[3]=*(unsigned short*)&t;
  *(short4*)p=*(short4*)u;
}

// ---------------- workspace offsets (bytes) ----------------
#define O_GX       0UL
#define O_QH       1310720UL
#define O_QNODE    1638400UL
#define O_RELLIN   1654784UL
#define O_WR       2270208UL
#define O_WMAX     2308864UL
#define O_WT       2309120UL
#define O_E2FS     2833408UL
#define O_PR       2964480UL
#define O_PRAGG    3095552UL
#define O_Q2EV     3226624UL
#define O_Q2EVB    3243008UL
#define O_RELSELF  3251200UL
#define O_NORM     3866624UL
#define O_WNXT     4390912UL
#define O_PRSUM    4440064UL
#define O_CNT      4440320UL
#define O_CUR      4571392UL
#define O_BSTART   4702464UL
#define O_BIDX     4834048UL
#define O_ELWPAD   5358336UL
#define O_FLAG     5522176UL
#define O_CVT      5522432UL   // 5393152 B
#define O_AGG      10915584UL  // bf16 16.7MB; A0 (21MB) aliases AGG+start of ENTSELF
#define O_ENTSELF  27692800UL
#define O_LEA      44470016UL
#define O_LEB      61247232UL
#define O_HEAD     78024448UL
#define O_F2EEMB   94801664UL  // end ~111.6MB

// canonical element offsets within O_CVT (all mult of 8)
#define C_ELB   0
#define C_RLW   256
#define C_RLB   153856
#define C_WIH   154112
#define C_WHH   461312   // frag-linear w_hh (262144 elems)
#define C_BIH   723456
#define C_BHH   724480
#define C_Q2EW  725504
#define C_Q2EB  922112
#define C_E2QW  922880
#define C_E2QB  1512704
#define C_E2EW  1513472
#define C_E2EB  2103296
#define C_KHW   2104064
#define C_KHB   2300672
#define C_KTW   2301440
#define C_KTB   2498048
#define C_KSW   2498816
#define C_KSB   2695424
#define C_SCW   2696192
#define C_SCB   2696448

// ---------------- dtype sniffer (verified r2) ----------------
__global__ __launch_bounds__(256) void k_sniff(const unsigned short* ee, int* flag){
  __shared__ int red[256];
  int c=0;
  for(int i=threadIdx.x;i<4096;i+=256){
    int ex=(ee[2*i]>>7)&0xFF;
    c += (ex>=192);
  }
  red[threadIdx.x]=c; __syncthreads();
  for(int o=128;o;o>>=1){ if(threadIdx.x<o) red[threadIdx.x]+=red[threadIdx.x+o]; __syncthreads(); }
  if(!threadIdx.x) flag[0] = (red[0]>64) ? 1 : 0;
}

// ---------------- batched weight canonicalization -> bf16 (tail-scale for e2q/e2e) ----------------
struct CvtJobs{ const void* src[20]; bf16* dst[20]; int n[20]; int sc[20]; };
__global__ __launch_bounds__(256) void k_cvt(CvtJobs J, const int* dfl){
  const int isf=*dfl;
  int j=blockIdx.y;
  int n=J.n[j];
  int i4=(blockIdx.x*256+threadIdx.x)*4;
  if(i4>=n) return;
  float m = (J.sc[j] && ((i4%768)>=512)) ? 3.f : 1.f;
  bf16* d=J.dst[j]+i4;
  if(isf){
    const float* s=(const float*)J.src[j]+i4;
    if(i4+4<=n){ float4 t=*(const float4*)s; st4bf(d,t.x*m,t.y*m,t.z*m,t.w*m); }
    else for(int r=0;i4+r<n;r++) d[r]=f2b(s[r]*m);
  } else {
    const bf16* s=(const bf16*)J.src[j]+i4;
    if(i4+4<=n){ float v[4]; ld4bf(s,v); st4bf(d,v[0]*m,v[1]*m,v[2]*m,v[3]*m); }
    else for(int r=0;i4+r<n;r++) d[r]=f2b(b2f(s[r])*m);
  }
}

// w_hh (1024x256) -> MFMA-fragment-linear: wf[gt][kt][lane][8], gate=gt*16+(lane&15), k=kt*32+(lane>>4)*8+j
__global__ __launch_bounds__(256) void k_cvtwhh(const void* src, bf16* wf, const int* dfl){
  const int isf=*dfl;
  int fid=blockIdx.x*256+threadIdx.x;        // 0..32767
  int lane=fid&63, kt=(fid>>6)&7, gt=fid>>9;
  int l16=lane&15, q=lane>>4;
  long so=(long)(gt*16+l16)*256 + kt*32 + q*8;
  float v[8];
  if(isf){ const float* s=(const float*)src+so;
    #pragma unroll
    for(int j=0;j<8;j++) v[j]=s[j];
  } else { const bf16* s=(const bf16*)src+so; ld4bf(s,v); ld4bf(s+4,v+4); }
  bf16* d=wf+(long)fid*8;
  st4bf(d,v[0],v[1],v[2],v[3]); st4bf(d+4,v[4],v[5],v[6],v[7]);
}

// entity_lin_w (256x300) -> padded bf16 (256x320)
__global__ __launch_bounds__(256) void k_cvtelw(const void* src, bf16* dst, const int* dfl){
  const int isf=*dfl;
  int r=blockIdx.x;
  for(int c=threadIdx.x;c<320;c+=256){
    float v=0.f;
    if(c<300) v = isf ? ((const float*)src)[r*300+c] : b2f(((const bf16*)src)[r*300+c]);
    dst[(long)r*320+c]=f2b(v);
  }
}

// gathered, padded A0[32768][320] = entity_emb[local_entity]
__global__ __launch_bounds__(128) void k_ga0(const int* idx, const void* emb, bf16* A0, const int* dfl){
  const int isf=*dfl;
  int row=blockIdx.x; int ent=idx[row]; int t=threadIdx.x;
  bf16* dst=A0+(long)row*320;
  if(t<75){
    float v[4];
    if(isf){ float4 x=*(const float4*)((const float*)emb+(long)ent*WDIM+t*4);
             v[0]=x.x;v[1]=x.y;v[2]=x.z;v[3]=x.w; }
    else ld4bf((const bf16*)emb+(long)ent*WDIM+t*4, v);
    st4bf(dst+t*4, v[0],v[1],v[2],v[3]);
  } else if(t<80){
    st4bf(dst+t*4, 0.f,0.f,0.f,0.f);
  }
}

// ---------------- CSR bucketing of facts by (b, f2e_ent) ----------------
__global__ __launch_bounds__(256) void k_cnt(const int* f2e, int* cnt){
  int i=blockIdx.x*256+threadIdx.x;
  atomicAdd(&cnt[((i>>13)<<11)+f2e[i]], 1);
}
__global__ __launch_bounds__(1024) void k_scan(const int* cnt, int* bstart){
  __shared__ int ps[1024];
  int t=threadIdx.x;
  int loc[32]; int s=0;
  #pragma unroll
  for(int j=0;j<32;j++){ loc[j]=s; s+=cnt[t*32+j]; }
  ps[t]=s; __syncthreads();
  for(int off=1;off<1024;off<<=1){
    int v=(t>=off)?ps[t-off]:0;
    __syncthreads(); ps[t]+=v; __syncthreads();
  }
  int base=(t? ps[t-1]:0);
  #pragma unroll
  for(int j=0;j<32;j++) bstart[t*32+j]=base+loc[j];
  if(t==1023) bstart[32768]=ps[1023];
}
__global__ __launch_bounds__(256) void k_fill(const int* f2e, const int* bstart, int* cur, int* bidx){
  int i=blockIdx.x*256+threadIdx.x;
  int key=((i>>13)<<11)+f2e[i];
  int pos=bstart[key]+atomicAdd(&cur[key],1);
  bidx[pos]=i;
}

// ---------------- gx = wemb[qtext] @ w_ih^T + b_ih + b_hh ----------------
__global__ __launch_bounds__(256) void k_gx(const int* qtext, const void* wemb,
    const bf16* wih, const bf16* bih, const bf16* bhh, float* gx, const int* dfl){
  const int isf=*dfl;
  int bt=blockIdx.x;
  __shared__ float xr[WDIM];
  int w=qtext[bt];
  for(int k4=threadIdx.x*4;k4<WDIM;k4+=1024){
    if(isf){ float4 t=*(const float4*)((const float*)wemb+(long)w*WDIM+k4);
             xr[k4]=t.x;xr[k4+1]=t.y;xr[k4+2]=t.z;xr[k4+3]=t.w; }
    else   { float v[4]; ld4bf((const bf16*)wemb+(long)w*WDIM+k4,v);
             xr[k4]=v[0];xr[k4+1]=v[1];xr[k4+2]=v[2];xr[k4+3]=v[3]; }
  }
  __syncthreads();
  #pragma unroll
  for(int s=0;s<4;s++){
    int g=threadIdx.x+256*s;
    float acc=b2f(bih[g])+b2f(bhh[g]);
    const bf16* wr=wih+(long)g*WDIM;
    for(int k4=0;k4<WDIM;k4+=4){
      float v[4]; ld4bf(wr+k4,v);
      acc+=v[0]*xr[k4]+v[1]*xr[k4+1]+v[2]*xr[k4+2]+v[3]*xr[k4+3];
    }
    gx[bt*1024+g]=acc;
  }
}

// ---------------- MFMA LSTM: ONE block, 8 waves, all 16 batches in M dim ----------------
#define WPAD 264
#define ZPAD 1032
__global__ __launch_bounds__(512) void k_lstm2(const float* gx, const bf16* wf,
    float* qh, float* qnode){
  __shared__ bf16  hb[16*WPAD];
  __shared__ float cs[16*256];
  __shared__ float zs[16*ZPAD];
  const int tid=threadIdx.x;
  for(int i=tid;i<16*WPAD;i+=512) hb[i]=f2b(0.f);
  for(int i=tid;i<16*256;i+=512) cs[i]=0.f;
  __syncthreads();
  const int wv=tid>>6, lane=tid&63, q=lane>>4, l16=lane&15;
  const int u=tid&255, b0=(tid>>8)*8;
  for(int t=0;t<QQ;t++){
    f32x4 acc[8];
    #pragma unroll
    for(int nt=0;nt<8;nt++) acc[nt]=(f32x4){0.f,0.f,0.f,0.f};
    #pragma unroll
    for(int kt=0;kt<8;kt++){
      bf16x8 af = *(const bf16x8*)(&hb[l16*WPAD + kt*32 + q*8]);
      #pragma unroll
      for(int nt=0;nt<8;nt++){
        int gt=wv*8+nt;
        bf16x8 bw = *(const bf16x8*)(wf + (((long)(gt*8+kt))*64 + lane)*8);
        acc[nt]=__builtin_amdgcn_mfma_f32_16x16x32_bf16(af,bw,acc[nt],0,0,0);
      }
    }
    #pragma unroll
    for(int nt=0;nt<8;nt++){
      int g=wv*128+nt*16+l16;
      #pragma unroll
      for(int r=0;r<4;r++) zs[(q*4+r)*ZPAD + g]=acc[nt][r];
    }
    __syncthreads();
    #pragma unroll
    for(int bb=0;bb<8;bb++){
      int b=b0+bb;
      const float* gp = gx + (long)(b*QQ+t)*1024;
      float zi=zs[b*ZPAD+u]     + gp[u];
      float zf=zs[b*ZPAD+256+u] + gp[256+u];
      float zg=zs[b*ZPAD+512+u] + gp[512+u];
      float zo=zs[b*ZPAD+768+u] + gp[768+u];
      float cv=sigm(zf)*cs[b*256+u]+sigm(zi)*tanhf(zg);
      cs[b*256+u]=cv;
      float hh=sigm(zo)*tanhf(cv);
      hb[b*WPAD+u]=f2b(hh);
      qh[(long)(b*QQ+t)*256+u]=hh;
      if(t==QQ-1) qnode[(b<<8)+u]=hh;
    }
    __syncthreads();
  }
}

// ---------------- rel_lin ----------------
__global__ __launch_bounds__(256) void k_rel_lin(const void* remb, const bf16* rlw,
    const bf16* rlb, float* rel_lin, const int* dfl){
  const int isf=*dfl;
  int r=blockIdx.x;
  __shared__ float rr[2*WDIM];
  for(int k4=threadIdx.x*4;k4<2*WDIM;k4+=1024){
    if(isf){ float4 t=*(const float4*)((const float*)remb+(long)r*2*WDIM+k4);
             rr[k4]=t.x;rr[k4+1]=t.y;rr[k4+2]=t.z;rr[k4+3]=t.w; }
    else   { float v[4]; ld4bf((const bf16*)remb+(long)r*2*WDIM+k4,v);
             rr[k4]=v[0];rr[k4+1]=v[1];rr[k4+2]=v[2];rr[k4+3]=v[3]; }
  }
  __syncthreads();
  int d=threadIdx.x;
  float acc=b2f(rlb[d]);
  const bf16* wr=rlw+(long)d*2*WDIM;
  for(int k4=0;k4<2*WDIM;k4+=4){
    float v[4]; ld4bf(wr+k4,v);
    acc+=v[0]*rr[k4]+v[1]*rr[k4+1]+v[2]*rr[k4+2]+v[3]*rr[k4+3];
  }
  rel_lin[r*DD+d]=acc;
}

// ---------------- sim + masked softmax + Wr (relation space) ----------------
__global__ __launch_bounds__(256) void k_simwr(const float* qh, const float* rel_lin,
    const int* qtext, float* Wr){
  int b = blockIdx.x, rc = blockIdx.y;
  __shared__ float qhb[QQ*DD];
  __shared__ float qm[QQ];
  for(int i=threadIdx.x;i<QQ*DD;i+=256) qhb[i]=qh[b*QQ*DD+i];
  if(threadIdx.x<QQ) qm[threadIdx.x] = (qtext[b*QQ+threadIdx.x]!=NWORD)?0.f:VERY_NEG_F;
  __syncthreads();
  int r = rc*256+threadIdx.x;
  if(r>=601) return;
  float s[QQ];
  #pragma unroll
  for(int q=0;q<QQ;q++) s[q]=0.f;
  for(int k=0;k<DD;k++){
    float rl = rel_lin[r*DD+k];
    #pragma unroll
    for(int q=0;q<QQ;q++) s[q] += qhb[q*DD+k]*rl;
  }
  float m=-1e30f;
  #pragma unroll
  for(int q=0;q<QQ;q++){ s[q]*=0.0625f; m=fmaxf(m, s[q]+qm[q]); }
  float sum=0.f, w=0.f;
  #pragma unroll
  for(int q=0;q<QQ;q++){ float p=expf(s[q]+qm[q]-m); sum+=p; w+=p*s[q]; }
  Wr[b*601+r] = w/sum;
}

// ---------------- Wmax / W_tilde / e2f_softmax / pr init ----------------
__global__ __launch_bounds__(256) void k_wmax(const float* Wr, const int* rel, float* wmax){
  int b=blockIdx.x; __shared__ float red[256];
  float m=-1e30f;
  for(int f=threadIdx.x;f<FF;f+=256) m=fmaxf(m, Wr[b*601+rel[b*FF+f]]);
  red[threadIdx.x]=m; __syncthreads();
  for(int o=128;o;o>>=1){ if(threadIdx.x<o) red[threadIdx.x]=fmaxf(red[threadIdx.x],red[threadIdx.x+o]); __syncthreads(); }
  if(!threadIdx.x) wmax[b]=red[0];
}
__global__ __launch_bounds__(256) void k_wt(const float* Wr, const int* rel,
    const float* wmax, const int* e2f, float* wt, float* e2fs){
  int i = blockIdx.x*256+threadIdx.x;
  int b = i>>13;
  float v = expf(Wr[b*601+rel[i]] - wmax[b]);
  wt[i]=v;
  atomicAdd(e2fs + (b<<11) + e2f[i], v);
}
__global__ __launch_bounds__(256) void k_prinit(const void* adj, float* pr, const int* dfl){
  const int isf=*dfl;
  int i4=(blockIdx.x*256+threadIdx.x)*4;
  if(isf){ *(float4*)(pr+i4)=*(const float4*)((const float*)adj+i4); }
  else { float v[4]; ld4bf((const bf16*)adj+i4,v);
         float4 t; t.x=v[0];t.y=v[1];t.z=v[2];t.w=v[3]; *(float4*)(pr+i4)=t; }
}

// ---------------- MFMA GEMM: C[M,256] = A[M,K] @ W[256,K]^T, no LDS ----------------
struct MG {
  const bf16* A; const bf16* W; const bf16* bias;
  bf16* out; int K;
  const bf16* Aq2; const bf16* Af2;
  const int* cnt; const bf16* addb;
};
template<int CONCAT,int EPI>
__global__ __launch_bounds__(256) void k_mgemm(MG p){
  const int m0 = blockIdx.x*64;
  const int wave = threadIdx.x>>6, lane = threadIdx.x&63;
  const int q = lane>>4, l16 = lane&15;
  const int n0 = wave*64;
  const int bidx_ = m0>>11;
  f32x4 acc[4][4];
  #pragma unroll
  for(int i=0;i<4;i++)
    #pragma unroll
    for(int j=0;j<4;j++) acc[i][j]=(f32x4){0.f,0.f,0.f,0.f};
  const int K=p.K;
  for(int k0=0;k0<K;k0+=32){
    int kk=k0+q*8;
    bf16x8 af[4], bw[4];
    #pragma unroll
    for(int mi=0;mi<4;mi++){
      int row=m0+mi*16+l16;
      const bf16* ap;
      if(CONCAT){
        if(kk<256)      ap=p.A  +(long)row*256+kk;
        else if(kk<512) ap=p.Aq2+(bidx_<<8)+(kk-256);
        else            ap=p.Af2+(long)row*256+(kk-512);
      } else ap=p.A+(long)row*K+kk;
      af[mi]=*(const bf16x8*)ap;
    }
    #pragma unroll
    for(int ni=0;ni<4;ni++)
      bw[ni]=*(const bf16x8*)(p.W+(long)(n0+ni*16+l16)*K+kk);
    #pragma unroll
    for(int mi=0;mi<4;mi++)
      #pragma unroll
      for(int ni=0;ni<4;ni++)
        acc[mi][ni]=__builtin_amdgcn_mfma_f32_16x16x32_bf16(af[mi],bw[ni],acc[mi][ni],0,0,0);
  }
  #pragma unroll
  for(int ni=0;ni<4;ni++){
    int col=n0+ni*16+l16;
    float bv=b2f(p.bias[col]);
    #pragma unroll
    for(int mi=0;mi<4;mi++){
      #pragma unroll
      for(int r=0;r<4;r++){
        int row=m0+mi*16+q*4+r;
        float v=acc[mi][ni][r];
        if(EPI==0) v+=bv;
        else if(EPI==1) v=fmaxf(v+bv,0.f);
        else {
          v += (float)p.cnt[row]*bv + b2f(p.addb[(long)row*256+col]);
          v=fmaxf(v,0.f);
        }
        p.out[(long)row*256+col]=f2b(v);
      }
    }
  }
}

// ---------------- per-layer small mats ----------------
__global__ __launch_bounds__(256) void k_small(const float* rel_lin, const bf16* selfw,
    const bf16* selfb, const float* qnode, const bf16* q2ew, const bf16* q2eb,
    float* relself, float* q2ev, bf16* q2evb){
  __shared__ float xr[DD];
  int d=threadIdx.x;
  if(blockIdx.x<601){
    int r=blockIdx.x;
    xr[d]=rel_lin[r*DD+d]; __syncthreads();
    float acc=b2f(selfb[d]);
    const bf16* wr=selfw+(long)d*DD;
    for(int k4=0;k4<DD;k4+=4){
      float v[4]; ld4bf(wr+k4,v);
      acc+=v[0]*xr[k4]+v[1]*xr[k4+1]+v[2]*xr[k4+2]+v[3]*xr[k4+3];
    }
    relself[r*DD+d]=acc;
  } else {
    int b=blockIdx.x-601;
    xr[d]=qnode[(b<<8)+d]; __syncthreads();
    float acc=b2f(q2eb[d]);
    const bf16* wr=q2ew+(long)d*DD;
    for(int k4=0;k4<DD;k4+=4){
      float v[4]; ld4bf(wr+k4,v);
      acc+=v[0]*xr[k4]+v[1]*xr[k4+1]+v[2]*xr[k4+2]+v[3]*xr[k4+3];
    }
    q2ev[(b<<8)+d]=acc;
    q2evb[(b<<8)+d]=f2b(acc);
  }
}

// ---------------- norm + pagerank numerator scatter ----------------
__global__ __launch_bounds__(256) void k_norm(const float* wt, const float* pr,
    const float* e2fs, const int* e2f, const int* f2e, float* normv, float* pragg){
  int i=blockIdx.x*256+threadIdx.x;
  int b=i>>13;
  int e=e2f[i];
  float v=wt[i]*pr[(b<<11)+e]/fmaxf(e2fs[(b<<11)+e],1e-10f);
  normv[i]=v;
  atomicAdd(pragg+(b<<11)+f2e[i], v);
}

// ---------------- segmented fact aggregation (atomic-free) ----------------
__global__ __launch_bounds__(256) void k_agg(const int* bstart, const int* bidx,
    const int* rel, const int* e2f, const float* normv, const float* relself,
    const bf16* head, bf16* agg){
  int eidx=blockIdx.x*4+(threadIdx.x>>6);
  int lane=threadIdx.x&63;
  int b=eidx>>11;
  float a0=0.f,a1=0.f,a2=0.f,a3=0.f;
  int s=bstart[eidx], e=bstart[eidx+1];
  for(int i=s;i<e;i++){
    int f=bidx[i];
    int r=rel[f]; int ent=e2f[f]; float nv=normv[f];
    float4 rs=*(const float4*)&relself[r*DD+lane*4];
    float hd[4]; ld4bf(head+(long)(((b<<11)+ent)*DD+lane*4),hd);
    a0+=fmaxf(rs.x+hd[0],0.f)*nv; a1+=fmaxf(rs.y+hd[1],0.f)*nv;
    a2+=fmaxf(rs.z+hd[2],0.f)*nv; a3+=fmaxf(rs.w+hd[3],0.f)*nv;
  }
  st4bf(agg+(long)eidx*DD+lane*4, a0,a1,a2,a3);
}

// ---------------- weighted row-sums (fused pagerank update) ----------------
__global__ __launch_bounds__(256) void k_wnxt(const float* pragg, float* pr, const bf16* le,
    const bf16* f2e, float* wnxt, float* prsum){
  int b=blockIdx.x, ch=blockIdx.y, d=threadIdx.x;
  float a1=0.f,a3=0.f,ap=0.f;
  int e0=ch*256;
  #pragma unroll 4
  for(int e=e0;e<e0+256;e++){
    int pe=(b<<11)+e;
    float p=0.8f*pragg[pe]+0.2f*pr[pe];
    if(d==0) pr[pe]=p;
    long base=(long)pe<<8;
    a1+=p*b2f(le[base+d]);
    a3+=p*b2f(f2e[base+d]);
    ap+=p;
  }
  atomicAdd(&wnxt[b*768+d],a1);
  atomicAdd(&wnxt[b*768+512+d],a3);
  if(d==0) atomicAdd(&prsum[b],ap);
}

// note: e2q_w tail cols pre-scaled by 3 at cvt -> xr segment 3 is plain a3
__global__ __launch_bounds__(256) void k_qnode(const float* wnxt, const float* prsum,
    const float* q2ev, const bf16* w, const bf16* bias, float* qnode){
  int b=blockIdx.x, d=threadIdx.x;
  __shared__ float xr[768];
  float ps=prsum[b];
  xr[d]=wnxt[b*768+d];
  xr[256+d]=ps*q2ev[(b<<8)+d];
  xr[512+d]=wnxt[b*768+512+d];
  __syncthreads();
  float acc=0.f;
  const bf16* wr=w+(long)d*768;
  for(int k4=0;k4<768;k4+=4){
    float v[4]; ld4bf(wr+k4,v);
    acc+=v[0]*xr[k4]+v[1]*xr[k4+1]+v[2]*xr[k4+2]+v[3]*xr[k4+3];
  }
  qnode[(b<<8)+d]=acc+ps*b2f(bias[d]);
}

// ---------------- score ----------------
__global__ __launch_bounds__(256) void k_score(const bf16* le, const bf16* sw,
    const bf16* sb, void* out, const int* dfl){
  const int isf=*dfl;
  int o=blockIdx.x*4 + (threadIdx.x>>6);
  int lane=threadIdx.x&63;
  float v[4],wv[4];
  ld4bf(le+(long)o*DD+lane*4,v); ld4bf(sw+lane*4,wv);
  float acc=v[0]*wv[0]+v[1]*wv[1]+v[2]*wv[2]+v[3]*wv[3];
  for(int off=32;off;off>>=1) acc+=__shfl_down(acc,off,64);
  if(!lane){
    float r=acc+b2f(sb[0]);
    if(isf) ((float*)out)[o]=r; else ((bf16*)out)[o]=f2b(r);
  }
}

// ---------------- host ----------------
extern "C" void kernel_launch(void* const* d_in, const int* in_sizes, int n_in,
                              void* d_out, int out_size, void* d_ws, size_t ws_size,
                              hipStream_t stream){
  const int*  local_entity=(const int*)d_in[0];
  const void* q2e_adj     =d_in[1];
  const int*  kb_fact_rel =(const int*)d_in[2];
  const int*  query_text  =(const int*)d_in[3];
  const int*  e2f_ent     =(const int*)d_in[5];
  const int*  f2e_ent     =(const int*)d_in[6];
  const void* word_emb    =d_in[7];
  const void* entity_emb  =d_in[8];
  const void* relation_emb=d_in[9];

  char* ws=(char*)d_ws;
  float* gx      =(float*)(ws+O_GX);
  float* qh      =(float*)(ws+O_QH);
  float* qnode   =(float*)(ws+O_QNODE);
  float* rel_lin =(float*)(ws+O_RELLIN);
  float* Wr      =(float*)(ws+O_WR);
  float* wmax    =(float*)(ws+O_WMAX);
  float* wt      =(float*)(ws+O_WT);
  float* e2fs    =(float*)(ws+O_E2FS);
  float* pr      =(float*)(ws+O_PR);
  float* pragg   =(float*)(ws+O_PRAGG);
  float* q2ev    =(float*)(ws+O_Q2EV);
  bf16*  q2evb   =(bf16*)(ws+O_Q2EVB);
  float* relself =(float*)(ws+O_RELSELF);
  float* normv   =(float*)(ws+O_NORM);
  float* wnxt    =(float*)(ws+O_WNXT);
  float* prsum   =(float*)(ws+O_PRSUM);
  int*   cnt     =(int*)(ws+O_CNT);
  int*   cur     =(int*)(ws+O_CUR);
  int*   bstart  =(int*)(ws+O_BSTART);
  int*   bidx    =(int*)(ws+O_BIDX);
  bf16*  elwpad  =(bf16*)(ws+O_ELWPAD);
  int*   dflag   =(int*)(ws+O_FLAG);
  bf16*  cw      =(bf16*)(ws+O_CVT);
  bf16*  agg     =(bf16*)(ws+O_AGG);
  bf16*  A0      =(bf16*)(ws+O_AGG);      // aliases agg + start of entself (pre-layer use only)
  bf16*  entself =(bf16*)(ws+O_ENTSELF);
  bf16*  leA     =(bf16*)(ws+O_LEA);
  bf16*  leB     =(bf16*)(ws+O_LEB);
  bf16*  headb   =(bf16*)(ws+O_HEAD);
  bf16*  f2eemb  =(bf16*)(ws+O_F2EEMB);

  k_sniff<<<1,256,0,stream>>>((const unsigned short*)entity_emb, dflag);

  CvtJobs J;
  int cntj=0;
  auto add=[&](int in_idx, long coff, int n, int sc){
    J.src[cntj]=d_in[in_idx]; J.dst[cntj]=cw+coff; J.n[cntj]=n; J.sc[cntj]=sc; cntj++;
  };
  add(11,C_ELB,256,0);
  add(12,C_RLW,153600,0);  add(13,C_RLB,256,0);
  add(14,C_WIH,307200,0);
  add(16,C_BIH,1024,0);    add(17,C_BHH,1024,0);
  add(18,C_Q2EW,196608,0); add(19,C_Q2EB,768,0);
  add(20,C_E2QW,589824,1); add(21,C_E2QB,768,0);
  add(22,C_E2EW,589824,1); add(23,C_E2EB,768,0);
  add(24,C_KHW,196608,0);  add(25,C_KHB,768,0);
  add(26,C_KTW,196608,0);  add(27,C_KTB,768,0);
  add(28,C_KSW,196608,0);  add(29,C_KSB,768,0);
  add(30,C_SCW,256,0);     add(31,C_SCB,1,0);
  k_cvt<<<dim3(576,20),256,0,stream>>>(J, dflag);
  k_cvtwhh<<<128,256,0,stream>>>(d_in[15], cw+C_WHH, dflag);
  k_cvtelw<<<256,256,0,stream>>>(d_in[10], elwpad, dflag);

  // CSR bucketing (fact graph is launch-constant); cnt+cur adjacent -> one memset
  hipMemsetAsync(cnt, 0, (size_t)2*BB*EE*4, stream);
  k_cnt <<<BB*FF/256,256,0,stream>>>(f2e_ent, cnt);
  k_scan<<<1,1024,0,stream>>>(cnt, bstart);
  k_fill<<<BB*FF/256,256,0,stream>>>(f2e_ent, bstart, cur, bidx);

  k_gx   <<<BB*QQ,256,0,stream>>>(query_text, word_emb, cw+C_WIH, cw+C_BIH, cw+C_BHH, gx, dflag);
  k_lstm2<<<1,512,0,stream>>>(gx, cw+C_WHH, qh, qnode);
  k_rel_lin<<<601,256,0,stream>>>(relation_emb, cw+C_RLW, cw+C_RLB, rel_lin, dflag);
  k_simwr<<<dim3(BB,3),256,0,stream>>>(qh, rel_lin, query_text, Wr);
  k_wmax <<<BB,256,0,stream>>>(Wr, kb_fact_rel, wmax);
  hipMemsetAsync(e2fs, 0, (size_t)BB*EE*4, stream);
  k_wt   <<<BB*FF/256,256,0,stream>>>(Wr, kb_fact_rel, wmax, e2f_ent, wt, e2fs);
  k_prinit<<<BB*EE/1024,256,0,stream>>>(q2e_adj, pr, dflag);

  // le = entity_emb[local_entity] @ elw^T + elb   (K padded to 320)
  k_ga0<<<BB*EE,128,0,stream>>>(local_entity, entity_emb, A0, dflag);
  {
    MG p{}; p.A=A0; p.W=elwpad; p.bias=cw+C_ELB; p.out=leA; p.K=320;
    k_mgemm<0,0><<<BB*EE/64,256,0,stream>>>(p);
  }

  bf16* le_cur=leA; bf16* le_nxt=leB;
  for(int i=0;i<3;i++){
    k_small<<<617,256,0,stream>>>(rel_lin, cw+C_KSW+(long)i*65536, cw+C_KSB+(long)i*256,
        qnode, cw+C_Q2EW+(long)i*65536, cw+C_Q2EB+(long)i*256, relself, q2ev, q2evb);
    {
      MG p{}; p.A=le_cur; p.W=cw+C_KHW+(long)i*65536; p.bias=cw+C_KHB+(long)i*256;
      p.out=headb; p.K=256;
      k_mgemm<0,0><<<BB*EE/64,256,0,stream>>>(p);
    }
    {
      MG p{}; p.A=le_cur; p.W=cw+C_KSW+(long)i*65536; p.bias=cw+C_KSB+(long)i*256;
      p.out=entself; p.K=256;
      k_mgemm<0,0><<<BB*EE/64,256,0,stream>>>(p);
    }
    hipMemsetAsync(pragg, 0, (size_t)BB*EE*4, stream);
    k_norm<<<BB*FF/256,256,0,stream>>>(wt, pr, e2fs, e2f_ent, f2e_ent, normv, pragg);
    k_agg <<<BB*EE/4,256,0,stream>>>(bstart, bidx, kb_fact_rel, e2f_ent, normv, relself, headb, agg);
    {
      MG p{}; p.A=agg; p.W=cw+C_KTW+(long)i*65536; p.bias=cw+C_KTB+(long)i*256;
      p.out=f2eemb; p.K=256; p.cnt=cnt; p.addb=entself;
      k_mgemm<0,2><<<BB*EE/64,256,0,stream>>>(p);
    }
    hipMemsetAsync(wnxt, 0, (size_t)(BB*768*4+256), stream);
    k_wnxt <<<dim3(BB,8),256,0,stream>>>(pragg, pr, le_cur, f2eemb, wnxt, prsum);
    k_qnode<<<BB,256,0,stream>>>(wnxt, prsum, q2ev, cw+C_E2QW+(long)i*196608, cw+C_E2QB+(long)i*256, qnode);
    {
      MG p{}; p.A=le_cur; p.W=cw+C_E2EW+(long)i*196608; p.bias=cw+C_E2EB+(long)i*256;
      p.out=le_nxt; p.K=768; p.Aq2=q2evb; p.Af2=f2eemb;
      k_mgemm<1,1><<<BB*EE/64,256,0,stream>>>(p);
    }
    bf16* t=le_cur; le_cur=le_nxt; le_nxt=t;
  }

  k_score<<<BB*EE/4,256,0,stream>>>(le_cur, cw+C_SCW, cw+C_SCB, d_out, dflag);
}